// Round 9
// baseline (252.479 us; speedup 1.0000x reference)
//
#include <hip/hip_runtime.h>
#include <hip/hip_bf16.h>
#include <math.h>

#define H3 768

// ---- ws layout (floats) ----
#define OFF_Q     0u        // 2048*256  (pre-summed q, atomic-accumulated)
#define OFF_K     524288u   // 128*256
#define OFF_UVK   557056u   // 128*512
#define OFF_SQ    622592u   // 2176 row sums (q rows 0..2047, k rows at 2048+bj)
#define OFF_SQ2   624768u   // 2176
#define OFF_WGU   626944u   // 256
#define OFF_WGV   627200u   // 256
#define OFF_CU    627456u   // 256
#define OFF_CV    627712u   // 256

// ---- scratch inside d_out's bias region (2097152 floats), all consumed
// before topk_bias overwrites it ----
#define BO_UVQ   0u          // 1048576  (2048x512 fp32)
#define BO_WQF   1048576u    // 262144   (Wq frags hi/lo, NTG=16, K=1024)
#define BO_WKF   1310720u    // 262144
#define BO_BPK   1572864u    // 131072   (qk-weight frags, 32x32x16 tiles, K=256)
#define BO_WQBF  1703936u    // 131072
#define BO_WKBF  1835008u    // 131072   end 1966080 < 2097152

typedef __attribute__((ext_vector_type(8))) short bf16x8;
typedef __attribute__((ext_vector_type(4))) float f32x4;
typedef __attribute__((ext_vector_type(16))) float f32x16;

__device__ __forceinline__ float bf2f(short s) {
    return __uint_as_float(((unsigned)(unsigned short)s) << 16);
}
union bfu { __hip_bfloat162 h; short2 s; };
__device__ __forceinline__ void split2(float a, float b, short* hi2, short* lo2) {
    bfu h; h.h = __float22bfloat162_rn(float2{a, b});
    float fa = bf2f(h.s.x), fb = bf2f(h.s.y);
    bfu l; l.h = __float22bfloat162_rn(float2{a - fa, b - fb});
    hi2[0] = h.s.x; hi2[1] = h.s.y;
    lo2[0] = l.s.x; lo2[1] = l.s.y;
}
__device__ __forceinline__ void split8(const float* v, bf16x8* vh, bf16x8* vl) {
    short h2[2], l2[2];
#pragma unroll
    for (int i = 0; i < 4; i++) {
        split2(v[2 * i], v[2 * i + 1], h2, l2);
        (*vh)[2 * i] = h2[0]; (*vh)[2 * i + 1] = h2[1];
        (*vl)[2 * i] = l2[0]; (*vl)[2 * i + 1] = l2[1];
    }
}

// branchless exact-gelu via A&S 7.1.26 erf (abs err ~1.5e-7)
__device__ __forceinline__ float gelu_fast(float v) {
    float ar = v * 0.70710678118654752440f;
    float a = fabsf(ar);
    float t = __builtin_amdgcn_rcpf(fmaf(0.3275911f, a, 1.0f));
    float p = fmaf(fmaf(fmaf(fmaf(1.061405429f, t, -1.453152027f), t,
                             1.421413741f), t, -0.284496736f), t, 0.254829592f) * t;
    float e = __expf(-ar * ar);
    float er = fmaf(-p, e, 1.0f);
    er = copysignf(er, ar);
    return 0.5f * v * (1.0f + er);
}

__device__ __forceinline__ float wave_reduce_add(float v) {
#pragma unroll
    for (int off = 32; off > 0; off >>= 1) v += __shfl_xor(v, off, 64);
    return v;
}

// ---- k1: prep — per-h scalars + weight frag scatters + q/K zeroing.
// R21: BPK branch re-scattered for 32x32x16 fragments (tiles ordered U,U,V,V
// per wave so U/V gelu pairing stays lane-local in main's epilogue).
// WQF/WKF/WQBF/WKBF (proj/uv, 16x16 shape) unchanged. ----
__global__ __launch_bounds__(256) void prep(const float* __restrict__ Wq,
                                            const float* __restrict__ Wk,
                                            const float* __restrict__ Wu,
                                            const float* __restrict__ Wv,
                                            const float* __restrict__ g,
                                            const float* __restrict__ lb,
                                            const float* __restrict__ bu,
                                            const float* __restrict__ bv,
                                            float* __restrict__ ws,
                                            float* __restrict__ bsc) {
    int tid = threadIdx.x;
    int bid = blockIdx.x;
    if (bid >= 512) {
        ws[(bid - 512) * 256 + tid] = 0.0f;   // zero q/K region [0, 557056)
        return;
    }
    if (bid < 64) {
        int h = bid * 4 + (tid >> 6);
        int lane = tid & 63;
        float su = 0.f, sv = 0.f, tu = 0.f, tv = 0.f;
#pragma unroll
        for (int i = 0; i < 12; i++) {
            int c = lane + 64 * i;
            float gg = g[c], bb = lb[c];
            float wu = Wu[h * H3 + c], wv = Wv[h * H3 + c];
            su += wu * gg; sv += wv * gg; tu += wu * bb; tv += wv * bb;
        }
        su = wave_reduce_add(su); sv = wave_reduce_add(sv);
        tu = wave_reduce_add(tu); tv = wave_reduce_add(tv);
        if (lane == 0) {
            ws[OFF_WGU + h] = su; ws[OFF_WGV + h] = sv;
            ws[OFF_CU + h] = tu + bu[h]; ws[OFF_CV + h] = tv + bv[h];
        }
        return;
    }
    float v8[8];
    bf16x8 vh, vl;
    if (bid < 320) {
        // WqF (64..191) / WkF (192..319): N=256, K=1024, NTG=16
        const float* W; bf16x8* dst;
        int idx;
        if (bid < 192) { idx = (bid - 64) * 256 + tid; W = Wq; dst = (bf16x8*)(bsc + BO_WQF); }
        else { idx = (bid - 192) * 256 + tid; W = Wk; dst = (bf16x8*)(bsc + BO_WKF); }
        int n = idx >> 7, k8 = idx & 127;
        const float* src = W + (size_t)n * 1024 + k8 * 8;
        *(float4*)&v8[0] = *(const float4*)src;
        *(float4*)&v8[4] = *(const float4*)(src + 4);
        split8(v8, &vh, &vl);
        int kc = k8 >> 2, grp = k8 & 3, lane = grp * 16 + (n & 15), ntg = n >> 4;
        size_t s0 = ((size_t)(kc * 16 + ntg) * 2) * 64 + lane;
        dst[s0] = vh; dst[s0 + 64] = vl;
        return;
    }
    if (bid < 448) {
        // WQBf (320..383) / WKBf (384..447): N=512, K=256, NTG=32 (16x16, uv/proj style)
        int idx, c0;
        bf16x8* dst;
        if (bid < 384) {
            idx = (bid - 320) * 256 + tid;
            c0 = (idx & 31) * 8;
            dst = (bf16x8*)(bsc + BO_WQBF);
        } else {
            idx = (bid - 384) * 256 + tid;
            c0 = 256 + (idx & 31) * 8;
            dst = (bf16x8*)(bsc + BO_WKBF);
        }
        int n = idx >> 5;
        int uv = (n < 256) ? 0 : 1;
        int h = (n < 256) ? n : n - 256;
        const float* W = uv ? Wv : Wu;
#pragma unroll
        for (int i = 0; i < 8; i++) v8[i] = W[(size_t)h * H3 + c0 + i] * g[c0 + i];
        split8(v8, &vh, &vl);
        int k8 = (c0 & 255) >> 3;
        int kc = k8 >> 2, grp = k8 & 3, lane = grp * 16 + (n & 15), ntg = n >> 4;
        size_t s0 = ((size_t)(kc * 32 + ntg) * 2) * 64 + lane;
        dst[s0] = vh; dst[s0 + 64] = vl;
        return;
    }
    // BPK (448..511): 32x32x16 B-fragments. n = tile*32 + col. Tile T (0..15):
    // wave wq = T>>2, tt = T&3; tt 0,1 = U channels, tt 2,3 = V; col c31;
    // h = wq*64 + (tt&1)*32 + c31. Fragment: lane = kg*32 + c31 holds
    // k = ks*16 + kg*8 + i (k8 = ks*2 + kg).
    {
        int idx = (bid - 448) * 256 + tid;
        int n = idx >> 5;
        int c0 = 512 + (idx & 31) * 8;
        int T = n >> 5, c31 = n & 31;
        int wq = T >> 2, tt = T & 3;
        int uv = tt >> 1;
        int h = wq * 64 + (tt & 1) * 32 + c31;
        const float* W = uv ? Wv : Wu;
#pragma unroll
        for (int i = 0; i < 8; i++) v8[i] = W[(size_t)h * H3 + c0 + i] * g[c0 + i];
        split8(v8, &vh, &vl);
        bf16x8* dst = (bf16x8*)(bsc + BO_BPK);
        int k8 = (c0 & 255) >> 3;
        int ks = k8 >> 1, kg = k8 & 1;
        int lane = kg * 32 + c31;
        size_t s0 = ((size_t)(ks * 16 + T) * 2) * 64 + lane;
        dst[s0] = vh; dst[s0 + 64] = vl;
    }
}

// ---- k2: projection MFMA — R12 verbatim: K-split x2, atomicAdd accumulate
// (exactly 2 commutative fp32 adds per element -> deterministic). 544 blocks
// = balanced 2.1/CU. ----
__global__ __launch_bounds__(256) void proj_mfma(const float* __restrict__ Q,
                                                 const float* __restrict__ Kin,
                                                 const float* __restrict__ bsc,
                                                 float* __restrict__ ws) {
    __shared__ __align__(16) short Ah[2][32 * 40], Al[2][32 * 40];
    int tid = threadIdx.x, bx = blockIdx.x, by = blockIdx.y, ks = blockIdx.z;
    const float* A; float* C; const bf16x8* BF;
    if (by < 64) {
        A = Q + (size_t)by * 32 * 1024;
        C = ws + OFF_Q + (size_t)by * 32 * 256;
        BF = (const bf16x8*)(bsc + BO_WQF);
    } else {
        A = Kin + (size_t)(by - 64) * 32 * 1024;
        C = ws + OFF_K + (size_t)(by - 64) * 32 * 256;
        BF = (const bf16x8*)(bsc + BO_WKF);
    }
    int w = tid >> 6, l = tid & 63, c15 = l & 15, grp = l >> 4;
    int mt = w & 1, np = w >> 1;
    int srow = tid >> 3, scol = (tid & 7) * 4;
    const float* arow = A + (size_t)srow * 1024 + ks * 512 + scol;
    f32x4 acc[2];
    acc[0] = (f32x4){0.f, 0.f, 0.f, 0.f};
    acc[1] = (f32x4){0.f, 0.f, 0.f, 0.f};
    float4 a4 = *(const float4*)&arow[0];
    for (int kc = 0; kc < 16; kc++) {
        int pb = kc & 1;
        short h4[4], l4[4];
        split2(a4.x, a4.y, &h4[0], &l4[0]);
        split2(a4.z, a4.w, &h4[2], &l4[2]);
        int ao = srow * 40 + scol;
        *(short4*)&Ah[pb][ao] = *(short4*)&h4[0];
        *(short4*)&Al[pb][ao] = *(short4*)&l4[0];
        if (kc < 15) a4 = *(const float4*)&arow[(kc + 1) * 32];
        __syncthreads();
        int fo = (mt * 16 + c15) * 40 + grp * 8;
        bf16x8 afh = *(const bf16x8*)&Ah[pb][fo];
        bf16x8 afl = *(const bf16x8*)&Al[pb][fo];
        int kcg = ks * 16 + kc;
        bf16x8 bh[2], bl[2];
#pragma unroll
        for (int i = 0; i < 2; i++) {
            int ntg = bx * 4 + 2 * np + i;
            size_t fi = ((size_t)(kcg * 16 + ntg) * 2) * 64 + l;
            bh[i] = BF[fi]; bl[i] = BF[fi + 64];
        }
#pragma unroll
        for (int i = 0; i < 2; i++)
            acc[i] = __builtin_amdgcn_mfma_f32_16x16x32_bf16(afl, bh[i], acc[i], 0, 0, 0);
#pragma unroll
        for (int i = 0; i < 2; i++)
            acc[i] = __builtin_amdgcn_mfma_f32_16x16x32_bf16(afh, bl[i], acc[i], 0, 0, 0);
#pragma unroll
        for (int i = 0; i < 2; i++)
            acc[i] = __builtin_amdgcn_mfma_f32_16x16x32_bf16(afh, bh[i], acc[i], 0, 0, 0);
    }
#pragma unroll
    for (int r = 0; r < 4; r++) {
        int rloc = mt * 16 + grp * 4 + r;
#pragma unroll
        for (int i = 0; i < 2; i++)
            atomicAdd(&C[(size_t)rloc * 256 + bx * 64 + (2 * np + i) * 16 + c15], acc[i][r]);
    }
}

// ---- k3: UV GEMM — R20: 32-row blocks, grid (8,68)=544 balanced (2.1/CU) ----
__global__ __launch_bounds__(256) void uv_mfma(float* __restrict__ ws,
                                               float* __restrict__ bsc) {
    __shared__ __align__(16) short Ah[32 * 40], Al[32 * 40];
    int tid = threadIdx.x, bx = blockIdx.x, by = blockIdx.y;
    const float* A; float* C; const bf16x8* BF; int sbase;
    if (by < 64) {
        A = ws + OFF_Q + (size_t)by * 32 * 256;
        C = bsc + BO_UVQ + (size_t)by * 32 * 512;
        BF = (const bf16x8*)(bsc + BO_WQBF);
        sbase = by * 32;
    } else {
        A = ws + OFF_K + (size_t)(by - 64) * 32 * 256;
        C = ws + OFF_UVK + (size_t)(by - 64) * 32 * 512;
        BF = (const bf16x8*)(bsc + BO_WKBF);
        sbase = 2048 + (by - 64) * 32;
    }
    int w = tid >> 6, l = tid & 63, c15 = l & 15, grp = l >> 4;
    int mt = w & 1, np = w >> 1;
    int srow = tid >> 3, scol = (tid & 7) * 4;
    f32x4 acc[2];
    acc[0] = (f32x4){0.f, 0.f, 0.f, 0.f};
    acc[1] = (f32x4){0.f, 0.f, 0.f, 0.f};
    float s1 = 0.f, s2 = 0.f;
    for (int kc = 0; kc < 8; kc++) {
        float4 a4 = *(const float4*)&A[(size_t)srow * 256 + kc * 32 + scol];
        if (bx == 0) {
            s1 += (a4.x + a4.y) + (a4.z + a4.w);
            s2 = fmaf(a4.x, a4.x, s2); s2 = fmaf(a4.y, a4.y, s2);
            s2 = fmaf(a4.z, a4.z, s2); s2 = fmaf(a4.w, a4.w, s2);
        }
        short h4v[4], l4v[4];
        split2(a4.x, a4.y, &h4v[0], &l4v[0]);
        split2(a4.z, a4.w, &h4v[2], &l4v[2]);
        int ao = srow * 40 + scol;
        *(short4*)&Ah[ao] = *(short4*)&h4v[0];
        *(short4*)&Al[ao] = *(short4*)&l4v[0];
        __syncthreads();
        int fo = (mt * 16 + c15) * 40 + grp * 8;
        bf16x8 afh = *(const bf16x8*)&Ah[fo];
        bf16x8 afl = *(const bf16x8*)&Al[fo];
        bf16x8 bh[2], bl[2];
#pragma unroll
        for (int i = 0; i < 2; i++) {
            int ntg = bx * 4 + np * 2 + i;
            size_t fi = ((size_t)(kc * 32 + ntg) * 2) * 64 + l;
            bh[i] = BF[fi]; bl[i] = BF[fi + 64];
        }
#pragma unroll
        for (int i = 0; i < 2; i++)
            acc[i] = __builtin_amdgcn_mfma_f32_16x16x32_bf16(afl, bh[i], acc[i], 0, 0, 0);
#pragma unroll
        for (int i = 0; i < 2; i++)
            acc[i] = __builtin_amdgcn_mfma_f32_16x16x32_bf16(afh, bl[i], acc[i], 0, 0, 0);
#pragma unroll
        for (int i = 0; i < 2; i++)
            acc[i] = __builtin_amdgcn_mfma_f32_16x16x32_bf16(afh, bh[i], acc[i], 0, 0, 0);
        __syncthreads();
    }
    if (bx == 0) {
        s1 += __shfl_xor(s1, 1, 64); s1 += __shfl_xor(s1, 2, 64); s1 += __shfl_xor(s1, 4, 64);
        s2 += __shfl_xor(s2, 1, 64); s2 += __shfl_xor(s2, 2, 64); s2 += __shfl_xor(s2, 4, 64);
        if ((tid & 7) == 0) {
            ws[OFF_SQ + sbase + srow] = s1;
            ws[OFF_SQ2 + sbase + srow] = s2;
        }
    }
#pragma unroll
    for (int i = 0; i < 2; i++)
#pragma unroll
        for (int r = 0; r < 4; r++)
            C[(size_t)(mt * 16 + grp * 4 + r) * 512 + bx * 64 + np * 32 + i * 16 + c15] = acc[i][r];
}

// ---- k4: main split-bf16 MFMA — R21: 32x32x16 shape. Same phase structure
// as R18 (stage -> 1 barrier -> MFMA -> epilogue), same LDS bytes, same load
// counts, same 128-reg acc (f32x16 acc[2][4]); MFMA count 768 -> 384 at
// 32k FLOP/inst (-17% matrix-pipe cycles, half the issue slots).
// Fragments: A/B row|col = l&31, k = (l>>5)*8+i; C/D col = l&31,
// row = (reg&3)+8*(reg>>2)+4*(l>>5) [m74/m101]. Tiles per wave: T=0,1 U-cols
// h=w*64+T*32+c31; T=2,3 V same h -> gelu pairing lane-local. ----
__global__ __launch_bounds__(256, 2) void main_mfma(const float* __restrict__ ws,
                                                    const float* __restrict__ bsc,
                                                    const float* __restrict__ Wo,
                                                    const float* __restrict__ bo,
                                                    float* __restrict__ logits) {
    __shared__ float kk[256];
    __shared__ __align__(16) short Ah[16384];   // 32 KB: [ks16][mt2][lane64][8]
    __shared__ __align__(16) short Al[16384];   // 32 KB
    __shared__ float mu_s[64], inv_s[64];
    __shared__ float part_s[4][64];
    int tid = threadIdx.x;
    int bidf = blockIdx.x;
    int ti = ((bidf & 7) << 1) | ((bidf >> 3) & 1);
    int j = (bidf >> 4) & 63;
    int b = bidf >> 10;
    int t0 = ti << 6;
    int bj = (b << 6) | j;
    int rot8 = bidf & 7;
    kk[tid] = ws[OFF_K + bj * 256 + tid];
    int w = tid >> 6, l = tid & 63, c31 = l & 31, half32 = l >> 5;
    int srow = tid >> 2, scol = (tid & 3) * 8;
    const float* qrow = ws + OFF_Q + (size_t)((b << 10) + t0 + srow) * 256 + scol;
    const bf16x8* bpk = (const bf16x8*)(bsc + BO_BPK);
    const float* UVQ = bsc + BO_UVQ;
    // per-lane channel scalars: 2 channels tch -> h = w*64 + tch*32 + c31
    float wgu_r[2], wgv_r[2], cu_r[2], cv_r[2], wo_r[2], uk_r[2], vk_r[2];
    int h2c[2];
#pragma unroll
    for (int tch = 0; tch < 2; tch++) {
        int h = (w << 6) | (tch << 5) | c31;
        h2c[tch] = h;
        wgu_r[tch] = ws[OFF_WGU + h]; wgv_r[tch] = ws[OFF_WGV + h];
        cu_r[tch] = ws[OFF_CU + h]; cv_r[tch] = ws[OFF_CV + h];
        wo_r[tch] = Wo[h];
        uk_r[tch] = ws[OFF_UVK + (size_t)bj * 512 + h];
        vk_r[tch] = ws[OFF_UVK + (size_t)bj * 512 + 256 + h];
    }
    // ---- MFMA C-in init: acc = uvq + uvk (affine base). T=tch is U, T=tch+2 is V.
    f32x16 acc[2][4];
#pragma unroll
    for (int mt2 = 0; mt2 < 2; mt2++) {
#pragma unroll
        for (int reg = 0; reg < 16; reg++) {
            int row = (b << 10) + t0 + mt2 * 32 + (reg & 3) + 8 * (reg >> 2) + 4 * half32;
            const float* uvq = UVQ + (size_t)row * 512;
#pragma unroll
            for (int tch = 0; tch < 2; tch++) {
                acc[mt2][tch][reg]     = uvq[h2c[tch]] + uk_r[tch];
                acc[mt2][tch + 2][reg] = uvq[256 + h2c[tch]] + vk_r[tch];
            }
        }
    }
    float s1 = 0.f, s2 = 0.f;
    // staging slot: value (srow, k=kc*32+scol+i) -> ks = kc*2+(scol>>4),
    // lane_st = ((scol>>3)&1)*32 + (srow&31), buffer index [ks*2 + (srow>>5)]
    int base = ((((scol >> 4) * 2 + (srow >> 5)) * 64 + ((scol >> 3) & 1) * 32 + (srow & 31)) << 3);
    __syncthreads();   // kk ready
    // ---- stage ALL 8 K-chunks (q * kk -> hi/lo bf16) ----
#pragma unroll
    for (int kc = 0; kc < 8; kc++) {
        float q8[8], kv[8];
        *(float4*)&q8[0] = *(const float4*)&qrow[kc * 32];
        *(float4*)&q8[4] = *(const float4*)&qrow[kc * 32 + 4];
        *(float4*)&kv[0] = *(const float4*)&kk[kc * 32 + scol];
        *(float4*)&kv[4] = *(const float4*)&kk[kc * 32 + scol + 4];
        bf16x8 vh, vl;
        short htmp[2], ltmp[2];
#pragma unroll
        for (int i = 0; i < 4; i++) {
            float a = q8[2 * i] * kv[2 * i];
            float c = q8[2 * i + 1] * kv[2 * i + 1];
            s1 += a + c;
            s2 = fmaf(a, a, s2); s2 = fmaf(c, c, s2);
            split2(a, c, htmp, ltmp);
            vh[2 * i] = htmp[0]; vh[2 * i + 1] = htmp[1];
            vl[2 * i] = ltmp[0]; vl[2 * i + 1] = ltmp[1];
        }
        *(bf16x8*)&Ah[base + kc * 2048] = vh;
        *(bf16x8*)&Al[base + kc * 2048] = vl;
    }
    // LN stats (before the single barrier)
    s1 += __shfl_xor(s1, 1, 64); s1 += __shfl_xor(s1, 2, 64);
    s2 += __shfl_xor(s2, 1, 64); s2 += __shfl_xor(s2, 2, 64);
    if ((tid & 3) == 0) {
        int row = (b << 10) + t0 + srow;
        float sq = s1 + ws[OFF_SQ + row] + ws[OFF_SQ + 2048 + bj];
        float sq2 = s2 + ws[OFF_SQ2 + row] + ws[OFF_SQ2 + 2048 + bj];
        float muv = sq * (1.0f / 768.0f);
        float ex2 = sq2 * (1.0f / 768.0f);
        mu_s[srow] = muv;
        inv_s[srow] = 1.0f / sqrtf(ex2 - muv * muv + 1e-5f);
    }
    __syncthreads();   // the ONLY staging barrier
    // ---- MFMA: 16 k-steps, rotated per block (L2 de-lockstep) ----
    int rotk = rot8 << 1;
#pragma unroll
    for (int ii = 0; ii < 16; ii++) {
        int ks = (ii + rotk) & 15;           // runtime — addresses only
        bf16x8 afh[2], afl[2];
#pragma unroll
        for (int mt2 = 0; mt2 < 2; mt2++) {
            int fo = ks * 1024 + mt2 * 512 + (l << 3);   // contiguous per-lane
            afh[mt2] = *(const bf16x8*)&Ah[fo];
            afl[mt2] = *(const bf16x8*)&Al[fo];
        }
        const bf16x8* bpc = bpk + (((size_t)(ks * 16 + w * 4)) << 7) + l;
#pragma unroll
        for (int T = 0; T < 4; T++) {
            bf16x8 bh = bpc[(size_t)T * 128];
            bf16x8 bl = bpc[(size_t)T * 128 + 64];
#pragma unroll
            for (int mt2 = 0; mt2 < 2; mt2++)
                acc[mt2][T] = __builtin_amdgcn_mfma_f32_32x32x16_bf16(afl[mt2], bh, acc[mt2][T], 0, 0, 0);
#pragma unroll
            for (int mt2 = 0; mt2 < 2; mt2++)
                acc[mt2][T] = __builtin_amdgcn_mfma_f32_32x32x16_bf16(afh[mt2], bl, acc[mt2][T], 0, 0, 0);
#pragma unroll
            for (int mt2 = 0; mt2 < 2; mt2++)
                acc[mt2][T] = __builtin_amdgcn_mfma_f32_32x32x16_bf16(afh[mt2], bh, acc[mt2][T], 0, 0, 0);
        }
    }
    // ---- epilogue: U = fma(invv, acc - muv*wgu, cu); gelu; 32-lane reduce ----
#pragma unroll
    for (int mt2 = 0; mt2 < 2; mt2++) {
#pragma unroll
        for (int reg = 0; reg < 16; reg++) {
            int rloc = mt2 * 32 + (reg & 3) + 8 * (reg >> 2) + 4 * half32;
            float muv = mu_s[rloc], invv = inv_s[rloc];
            float part = 0.f;
#pragma unroll
            for (int tch = 0; tch < 2; tch++) {
                float U = fmaf(invv, fmaf(-muv, wgu_r[tch], acc[mt2][tch][reg]), cu_r[tch]);
                float V = fmaf(invv, fmaf(-muv, wgv_r[tch], acc[mt2][tch + 2][reg]), cv_r[tch]);
                part = fmaf(wo_r[tch] * U, gelu_fast(V), part);
            }
            part += __shfl_xor(part, 1, 64);
            part += __shfl_xor(part, 2, 64);
            part += __shfl_xor(part, 4, 64);
            part += __shfl_xor(part, 8, 64);
            part += __shfl_xor(part, 16, 64);
            if (c31 == 0) part_s[w][rloc] = part;
        }
    }
    __syncthreads();
    if (tid < 64) {
        float v = bo[0] + part_s[0][tid] + part_s[1][tid] + part_s[2][tid] + part_s[3][tid];
        logits[(size_t)((b << 10) + t0 + tid) * 64 + j] = v;
    }
}

// ---- k5: topk + softmax + bias expansion; 4 rows/block; pow2 fast path ----
__global__ __launch_bounds__(256) void topk_bias(const float* __restrict__ logits,
                                                 float* __restrict__ bias,
                                                 const int* __restrict__ p_cl,
                                                 const int* __restrict__ p_L) {
    int wv = threadIdx.x >> 6, lane = threadIdx.x & 63;
    int row = blockIdx.x * 4 + wv;
    int t = row & 1023;
    __shared__ float pcb[4][64];
    float L = logits[(size_t)row * 64 + lane];
    float mx = L;
#pragma unroll
    for (int off = 32; off > 0; off >>= 1) mx = fmaxf(mx, __shfl_xor(mx, off, 64));
    float e = expf(L - mx);
    float s = wave_reduce_add(e);
    pcb[wv][lane] = -8.0f * (1.0f - e / s);
    bool valid = (lane >= 5) && ((lane - 5) <= t);
    float val = (lane >= 5) ? (valid ? L : -INFINITY) : -INFINITY;
    int idv = (lane >= 5) ? lane : (1 << 28);
    unsigned long long selmask = 0x1Full;
    for (int it = 0; it < 11; it++) {
        float bv = val; int bi = idv;
#pragma unroll
        for (int off = 32; off > 0; off >>= 1) {
            float ov = __shfl_xor(bv, off, 64);
            int oi = __shfl_xor(bi, off, 64);
            if (ov > bv || (ov == bv && oi < bi)) { bv = ov; bi = oi; }
        }
        selmask |= 1ull << bi;
        if (lane == bi) { val = -INFINITY; idv = (1 << 27); }
    }
    int clen = p_cl[0], Lctx = p_L[0];
    int nch1 = (Lctx + clen - 1) / clen - 1;
    bool p2 = (clen & (clen - 1)) == 0;
    int sh = 31 - __clz(clen);
    float* brow = bias + (size_t)row * Lctx;
    if ((Lctx & 3) == 0) {
        float4* brow4 = (float4*)brow;
        for (int q = lane; q < (Lctx >> 2); q += 64) {
            float o[4];
#pragma unroll
            for (int i = 0; i < 4; i++) {
                int ll = 4 * q + i;
                unsigned cq = p2 ? ((unsigned)ll >> sh) : ((unsigned)ll / (unsigned)clen);
                int c = min(min(cq, (unsigned)nch1), 63u);
                float v;
                if (ll > t) v = -1e30f;   // finite sentinel: ref -inf, diff must stay non-nan
                else if ((selmask >> c) & 1ull) v = 0.0f;
                else v = pcb[wv][c];
                o[i] = v;
            }
            brow4[q] = *(float4*)&o[0];
        }
    } else {
        for (int ll = lane; ll < Lctx; ll += 64) {
            unsigned cq = p2 ? ((unsigned)ll >> sh) : ((unsigned)ll / (unsigned)clen);
            int c = min(min(cq, (unsigned)nch1), 63u);
            float v;
            if (ll > t) v = -1e30f;
            else if ((selmask >> c) & 1ull) v = 0.0f;
            else v = pcb[wv][c];
            brow[ll] = v;
        }
    }
}

extern "C" void kernel_launch(void* const* d_in, const int* in_sizes, int n_in,
                              void* d_out, int out_size, void* d_ws, size_t ws_size,
                              hipStream_t stream) {
    const float* Q   = (const float*)d_in[0];
    const float* Kin = (const float*)d_in[1];
    const float* Wq  = (const float*)d_in[2];
    const float* Wk  = (const float*)d_in[3];
    const float* g   = (const float*)d_in[4];
    const float* lb  = (const float*)d_in[5];
    const float* Wu  = (const float*)d_in[6];
    const float* bu  = (const float*)d_in[7];
    const float* Wv  = (const float*)d_in[8];
    const float* bv  = (const float*)d_in[9];
    const float* Wo  = (const float*)d_in[10];
    const float* bo  = (const float*)d_in[11];
    const int* p_cl  = (const int*)d_in[12];
    const int* p_L   = (const int*)d_in[13];
    float* ws = (float*)d_ws;
    float* logits = (float*)d_out;
    float* bias = (float*)d_out + (size_t)2 * 1024 * 64;   // 131072

    prep<<<2688, 256, 0, stream>>>(Wq, Wk, Wu, Wv, g, lb, bu, bv, ws, bias);
    proj_mfma<<<dim3(4, 68, 2), 256, 0, stream>>>(Q, Kin, bias, ws);
    uv_mfma<<<dim3(8, 68), 256, 0, stream>>>(ws, bias);
    main_mfma<<<2048, 256, 0, stream>>>(ws, bias, Wo, bo, logits);
    topk_bias<<<512, 256, 0, stream>>>(logits, bias, p_cl, p_L);
}

// Round 10
// 224.672 us; speedup vs baseline: 1.1238x; 1.1238x over previous
//
#include <hip/hip_runtime.h>
#include <hip/hip_bf16.h>
#include <math.h>

#define H3 768

// ---- ws layout (floats) ----
#define OFF_Q     0u        // 2048*256  (pre-summed q, atomic-accumulated)
#define OFF_K     524288u   // 128*256
#define OFF_UVK   557056u   // 128*512
#define OFF_SQ    622592u   // 2176 row sums (q rows 0..2047, k rows at 2048+bj)
#define OFF_SQ2   624768u   // 2176
#define OFF_WGU   626944u   // 256
#define OFF_WGV   627200u   // 256
#define OFF_CU    627456u   // 256
#define OFF_CV    627712u   // 256

// ---- scratch inside d_out's bias region (2097152 floats), all consumed
// before topk_bias overwrites it ----
#define BO_UVQ   0u          // 1048576  (2048x512 fp32)
#define BO_WQF   1048576u    // 262144   (Wq frags hi/lo, NTG=16, K=1024)
#define BO_WKF   1310720u    // 262144
#define BO_BPK   1572864u    // 131072   (qk-weight frags, NTG=32, K=256)
#define BO_WQBF  1703936u    // 131072
#define BO_WKBF  1835008u    // 131072   end 1966080 < 2097152

typedef __attribute__((ext_vector_type(8))) short bf16x8;
typedef __attribute__((ext_vector_type(4))) float f32x4;

__device__ __forceinline__ float bf2f(short s) {
    return __uint_as_float(((unsigned)(unsigned short)s) << 16);
}
union bfu { __hip_bfloat162 h; short2 s; };
__device__ __forceinline__ void split2(float a, float b, short* hi2, short* lo2) {
    bfu h; h.h = __float22bfloat162_rn(float2{a, b});
    float fa = bf2f(h.s.x), fb = bf2f(h.s.y);
    bfu l; l.h = __float22bfloat162_rn(float2{a - fa, b - fb});
    hi2[0] = h.s.x; hi2[1] = h.s.y;
    lo2[0] = l.s.x; lo2[1] = l.s.y;
}
__device__ __forceinline__ void split8(const float* v, bf16x8* vh, bf16x8* vl) {
    short h2[2], l2[2];
#pragma unroll
    for (int i = 0; i < 4; i++) {
        split2(v[2 * i], v[2 * i + 1], h2, l2);
        (*vh)[2 * i] = h2[0]; (*vh)[2 * i + 1] = h2[1];
        (*vl)[2 * i] = l2[0]; (*vl)[2 * i + 1] = l2[1];
    }
}

// branchless exact-gelu via A&S 7.1.26 erf (abs err ~1.5e-7)
__device__ __forceinline__ float gelu_fast(float v) {
    float ar = v * 0.70710678118654752440f;
    float a = fabsf(ar);
    float t = __builtin_amdgcn_rcpf(fmaf(0.3275911f, a, 1.0f));
    float p = fmaf(fmaf(fmaf(fmaf(1.061405429f, t, -1.453152027f), t,
                             1.421413741f), t, -0.284496736f), t, 0.254829592f) * t;
    float e = __expf(-ar * ar);
    float er = fmaf(-p, e, 1.0f);
    er = copysignf(er, ar);
    return 0.5f * v * (1.0f + er);
}

__device__ __forceinline__ float wave_reduce_add(float v) {
#pragma unroll
    for (int off = 32; off > 0; off >>= 1) v += __shfl_xor(v, off, 64);
    return v;
}

// ---- k1: prep — R12 verbatim: per-h scalars + weight frag scatters + q/K
// zeroing (zeroing blocks run concurrently with scatter work) ----
__global__ __launch_bounds__(256) void prep(const float* __restrict__ Wq,
                                            const float* __restrict__ Wk,
                                            const float* __restrict__ Wu,
                                            const float* __restrict__ Wv,
                                            const float* __restrict__ g,
                                            const float* __restrict__ lb,
                                            const float* __restrict__ bu,
                                            const float* __restrict__ bv,
                                            float* __restrict__ ws,
                                            float* __restrict__ bsc) {
    int tid = threadIdx.x;
    int bid = blockIdx.x;
    if (bid >= 512) {
        ws[(bid - 512) * 256 + tid] = 0.0f;   // zero q/K region [0, 557056)
        return;
    }
    if (bid < 64) {
        int h = bid * 4 + (tid >> 6);
        int lane = tid & 63;
        float su = 0.f, sv = 0.f, tu = 0.f, tv = 0.f;
#pragma unroll
        for (int i = 0; i < 12; i++) {
            int c = lane + 64 * i;
            float gg = g[c], bb = lb[c];
            float wu = Wu[h * H3 + c], wv = Wv[h * H3 + c];
            su += wu * gg; sv += wv * gg; tu += wu * bb; tv += wv * bb;
        }
        su = wave_reduce_add(su); sv = wave_reduce_add(sv);
        tu = wave_reduce_add(tu); tv = wave_reduce_add(tv);
        if (lane == 0) {
            ws[OFF_WGU + h] = su; ws[OFF_WGV + h] = sv;
            ws[OFF_CU + h] = tu + bu[h]; ws[OFF_CV + h] = tv + bv[h];
        }
        return;
    }
    float v8[8];
    bf16x8 vh, vl;
    if (bid < 320) {
        // WqF (64..191) / WkF (192..319): N=256, K=1024, NTG=16
        const float* W; bf16x8* dst;
        int idx;
        if (bid < 192) { idx = (bid - 64) * 256 + tid; W = Wq; dst = (bf16x8*)(bsc + BO_WQF); }
        else { idx = (bid - 192) * 256 + tid; W = Wk; dst = (bf16x8*)(bsc + BO_WKF); }
        int n = idx >> 7, k8 = idx & 127;
        const float* src = W + (size_t)n * 1024 + k8 * 8;
        *(float4*)&v8[0] = *(const float4*)src;
        *(float4*)&v8[4] = *(const float4*)(src + 4);
        split8(v8, &vh, &vl);
        int kc = k8 >> 2, grp = k8 & 3, lane = grp * 16 + (n & 15), ntg = n >> 4;
        size_t s0 = ((size_t)(kc * 16 + ntg) * 2) * 64 + lane;
        dst[s0] = vh; dst[s0 + 64] = vl;
        return;
    }
    // N=512, K=256, NTG=32 frag matrices from Wu/Wv*g
    int idx, c0;
    bf16x8* dst;
    int n;
    if (bid < 384) {        // WQBf
        idx = (bid - 320) * 256 + tid;
        n = idx >> 5; c0 = (idx & 31) * 8;
        dst = (bf16x8*)(bsc + BO_WQBF);
    } else if (bid < 448) { // WKBf
        idx = (bid - 384) * 256 + tid;
        n = idx >> 5; c0 = 256 + (idx & 31) * 8;
        dst = (bf16x8*)(bsc + BO_WKBF);
    } else {                // BPK (interleaved U/V n-mapping)
        idx = (bid - 448) * 256 + tid;
        n = idx >> 5; c0 = 512 + (idx & 31) * 8;
        dst = (bf16x8*)(bsc + BO_BPK);
    }
    int h, uv;
    if (bid < 448) { uv = (n < 256) ? 0 : 1; h = (n < 256) ? n : n - 256; }
    else {
        int ntg0 = n >> 4, cc = n & 15;
        uv = ntg0 & 1;
        h = ((ntg0 >> 3) << 6) | (((ntg0 >> 1) & 3) << 4) | cc;
    }
    const float* W = uv ? Wv : Wu;
#pragma unroll
    for (int i = 0; i < 8; i++) v8[i] = W[(size_t)h * H3 + c0 + i] * g[c0 + i];
    split8(v8, &vh, &vl);
    int k8 = (c0 & 255) >> 3;
    int kc = k8 >> 2, grp = k8 & 3, lane = grp * 16 + (n & 15), ntg = n >> 4;
    size_t s0 = ((size_t)(kc * 32 + ntg) * 2) * 64 + lane;
    dst[s0] = vh; dst[s0 + 64] = vl;
}

// ---- k2: projection MFMA — R12 verbatim: K-split x2, atomicAdd accumulate
// (exactly 2 commutative fp32 adds per element -> deterministic). 544 blocks
// = balanced 2.1/CU. ----
__global__ __launch_bounds__(256) void proj_mfma(const float* __restrict__ Q,
                                                 const float* __restrict__ Kin,
                                                 const float* __restrict__ bsc,
                                                 float* __restrict__ ws) {
    __shared__ __align__(16) short Ah[2][32 * 40], Al[2][32 * 40];
    int tid = threadIdx.x, bx = blockIdx.x, by = blockIdx.y, ks = blockIdx.z;
    const float* A; float* C; const bf16x8* BF;
    if (by < 64) {
        A = Q + (size_t)by * 32 * 1024;
        C = ws + OFF_Q + (size_t)by * 32 * 256;
        BF = (const bf16x8*)(bsc + BO_WQF);
    } else {
        A = Kin + (size_t)(by - 64) * 32 * 1024;
        C = ws + OFF_K + (size_t)(by - 64) * 32 * 256;
        BF = (const bf16x8*)(bsc + BO_WKF);
    }
    int w = tid >> 6, l = tid & 63, c15 = l & 15, grp = l >> 4;
    int mt = w & 1, np = w >> 1;
    int srow = tid >> 3, scol = (tid & 7) * 4;
    const float* arow = A + (size_t)srow * 1024 + ks * 512 + scol;
    f32x4 acc[2];
    acc[0] = (f32x4){0.f, 0.f, 0.f, 0.f};
    acc[1] = (f32x4){0.f, 0.f, 0.f, 0.f};
    float4 a4 = *(const float4*)&arow[0];
    for (int kc = 0; kc < 16; kc++) {
        int pb = kc & 1;
        short h4[4], l4[4];
        split2(a4.x, a4.y, &h4[0], &l4[0]);
        split2(a4.z, a4.w, &h4[2], &l4[2]);
        int ao = srow * 40 + scol;
        *(short4*)&Ah[pb][ao] = *(short4*)&h4[0];
        *(short4*)&Al[pb][ao] = *(short4*)&l4[0];
        if (kc < 15) a4 = *(const float4*)&arow[(kc + 1) * 32];
        __syncthreads();
        int fo = (mt * 16 + c15) * 40 + grp * 8;
        bf16x8 afh = *(const bf16x8*)&Ah[pb][fo];
        bf16x8 afl = *(const bf16x8*)&Al[pb][fo];
        int kcg = ks * 16 + kc;
        bf16x8 bh[2], bl[2];
#pragma unroll
        for (int i = 0; i < 2; i++) {
            int ntg = bx * 4 + 2 * np + i;
            size_t fi = ((size_t)(kcg * 16 + ntg) * 2) * 64 + l;
            bh[i] = BF[fi]; bl[i] = BF[fi + 64];
        }
#pragma unroll
        for (int i = 0; i < 2; i++)
            acc[i] = __builtin_amdgcn_mfma_f32_16x16x32_bf16(afl, bh[i], acc[i], 0, 0, 0);
#pragma unroll
        for (int i = 0; i < 2; i++)
            acc[i] = __builtin_amdgcn_mfma_f32_16x16x32_bf16(afh, bl[i], acc[i], 0, 0, 0);
#pragma unroll
        for (int i = 0; i < 2; i++)
            acc[i] = __builtin_amdgcn_mfma_f32_16x16x32_bf16(afh, bh[i], acc[i], 0, 0, 0);
    }
#pragma unroll
    for (int r = 0; r < 4; r++) {
        int rloc = mt * 16 + grp * 4 + r;
#pragma unroll
        for (int i = 0; i < 2; i++)
            atomicAdd(&C[(size_t)rloc * 256 + bx * 64 + (2 * np + i) * 16 + c15], acc[i][r]);
    }
}

// ---- k3: UV GEMM — R22: R20's balanced 32-row blocks (grid (8,68)=544,
// 2.1/CU) + proj-style double-buffered LDS: ONE barrier per kc (was 2) and
// next a4 prefetched before the barrier. Stats/MFMA/C-write order unchanged
// (numerics identical to R20). LDS 5->10KB, still 8 blocks/CU. ----
__global__ __launch_bounds__(256) void uv_mfma(float* __restrict__ ws,
                                               float* __restrict__ bsc) {
    __shared__ __align__(16) short Ah[2][32 * 40], Al[2][32 * 40];
    int tid = threadIdx.x, bx = blockIdx.x, by = blockIdx.y;
    const float* A; float* C; const bf16x8* BF; int sbase;
    if (by < 64) {
        A = ws + OFF_Q + (size_t)by * 32 * 256;
        C = bsc + BO_UVQ + (size_t)by * 32 * 512;
        BF = (const bf16x8*)(bsc + BO_WQBF);
        sbase = by * 32;
    } else {
        A = ws + OFF_K + (size_t)(by - 64) * 32 * 256;
        C = ws + OFF_UVK + (size_t)(by - 64) * 32 * 512;
        BF = (const bf16x8*)(bsc + BO_WKBF);
        sbase = 2048 + (by - 64) * 32;
    }
    int w = tid >> 6, l = tid & 63, c15 = l & 15, grp = l >> 4;
    int mt = w & 1, np = w >> 1;
    int srow = tid >> 3, scol = (tid & 7) * 4;
    const float* arow = A + (size_t)srow * 256 + scol;
    f32x4 acc[2];
    acc[0] = (f32x4){0.f, 0.f, 0.f, 0.f};
    acc[1] = (f32x4){0.f, 0.f, 0.f, 0.f};
    float s1 = 0.f, s2 = 0.f;
    float4 a4 = *(const float4*)&arow[0];
    for (int kc = 0; kc < 8; kc++) {
        int pb = kc & 1;
        if (bx == 0) {
            s1 += (a4.x + a4.y) + (a4.z + a4.w);
            s2 = fmaf(a4.x, a4.x, s2); s2 = fmaf(a4.y, a4.y, s2);
            s2 = fmaf(a4.z, a4.z, s2); s2 = fmaf(a4.w, a4.w, s2);
        }
        short h4v[4], l4v[4];
        split2(a4.x, a4.y, &h4v[0], &l4v[0]);
        split2(a4.z, a4.w, &h4v[2], &l4v[2]);
        int ao = srow * 40 + scol;
        *(short4*)&Ah[pb][ao] = *(short4*)&h4v[0];
        *(short4*)&Al[pb][ao] = *(short4*)&l4v[0];
        if (kc < 7) a4 = *(const float4*)&arow[(kc + 1) * 32];
        __syncthreads();
        int fo = (mt * 16 + c15) * 40 + grp * 8;
        bf16x8 afh = *(const bf16x8*)&Ah[pb][fo];
        bf16x8 afl = *(const bf16x8*)&Al[pb][fo];
        bf16x8 bh[2], bl[2];
#pragma unroll
        for (int i = 0; i < 2; i++) {
            int ntg = bx * 4 + np * 2 + i;
            size_t fi = ((size_t)(kc * 32 + ntg) * 2) * 64 + l;
            bh[i] = BF[fi]; bl[i] = BF[fi + 64];
        }
#pragma unroll
        for (int i = 0; i < 2; i++)
            acc[i] = __builtin_amdgcn_mfma_f32_16x16x32_bf16(afl, bh[i], acc[i], 0, 0, 0);
#pragma unroll
        for (int i = 0; i < 2; i++)
            acc[i] = __builtin_amdgcn_mfma_f32_16x16x32_bf16(afh, bl[i], acc[i], 0, 0, 0);
#pragma unroll
        for (int i = 0; i < 2; i++)
            acc[i] = __builtin_amdgcn_mfma_f32_16x16x32_bf16(afh, bh[i], acc[i], 0, 0, 0);
    }
    if (bx == 0) {
        s1 += __shfl_xor(s1, 1, 64); s1 += __shfl_xor(s1, 2, 64); s1 += __shfl_xor(s1, 4, 64);
        s2 += __shfl_xor(s2, 1, 64); s2 += __shfl_xor(s2, 2, 64); s2 += __shfl_xor(s2, 4, 64);
        if ((tid & 7) == 0) {
            ws[OFF_SQ + sbase + srow] = s1;
            ws[OFF_SQ2 + sbase + srow] = s2;
        }
    }
#pragma unroll
    for (int i = 0; i < 2; i++)
#pragma unroll
        for (int r = 0; r < 4; r++)
            C[(size_t)(mt * 16 + grp * 4 + r) * 512 + bx * 64 + np * 32 + i * 16 + c15] = acc[i][r];
}

// ---- k4: main split-bf16 MFMA — R18 verbatim (best verified: 119.8us).
// Fragment-major A-tile (R17) + affine base in MFMA C-in (R18). Monolithic
// acc[4][8] in AGPRs; 16x16x32 shape (32x32x16 regressed: 2-way dep chains).
__global__ __launch_bounds__(256, 2) void main_mfma(const float* __restrict__ ws,
                                                    const float* __restrict__ bsc,
                                                    const float* __restrict__ Wo,
                                                    const float* __restrict__ bo,
                                                    float* __restrict__ logits) {
    __shared__ float kk[256];
    __shared__ __align__(16) short Ah[8][64 * 32];   // 32 KB (fragment-major)
    __shared__ __align__(16) short Al[8][64 * 32];   // 32 KB
    __shared__ float mu_s[64], inv_s[64];
    __shared__ float part_s[4][64];
    int tid = threadIdx.x;
    int bidf = blockIdx.x;
    int ti = ((bidf & 7) << 1) | ((bidf >> 3) & 1);
    int j = (bidf >> 4) & 63;
    int b = bidf >> 10;
    int t0 = ti << 6;
    int bj = (b << 6) | j;
    int rot8 = bidf & 7;
    kk[tid] = ws[OFF_K + bj * 256 + tid];
    int w = tid >> 6, l = tid & 63, c15 = l & 15, grp = l >> 4;
    int srow = tid >> 2, scol = (tid & 3) * 8;
    const float* qrow = ws + OFF_Q + (size_t)((b << 10) + t0 + srow) * 256 + scol;
    const bf16x8* bpk = (const bf16x8*)(bsc + BO_BPK);
    const float* UVQ = bsc + BO_UVQ;
    int ntg0 = w * 8;
    // per-channel scalars + h mapping (early: consumed by acc-init + epilogue)
    float wgu_r[4], wgv_r[4], cu_r[4], cv_r[4], wo_r[4], uk_r[4], vk_r[4];
    int h4[4];
#pragma unroll
    for (int a = 0; a < 4; a++) {
        int h = (w << 6) | (a << 4) | c15;
        h4[a] = h;
        wgu_r[a] = ws[OFF_WGU + h]; wgv_r[a] = ws[OFF_WGV + h];
        cu_r[a] = ws[OFF_CU + h]; cv_r[a] = ws[OFF_CV + h];
        wo_r[a] = Wo[h];
        uk_r[a] = ws[OFF_UVK + (size_t)bj * 512 + h];
        vk_r[a] = ws[OFF_UVK + (size_t)bj * 512 + 256 + h];
    }
    // ---- MFMA C-in init: acc = uvq + uvk (affine base; mu-term stays in
    // epilogue since mu isn't known yet). Loads overlap staging latency. ----
    f32x4 acc[4][8];
#pragma unroll
    for (int mt = 0; mt < 4; mt++) {
#pragma unroll
        for (int r4 = 0; r4 < 4; r4++) {
            int row = (b << 10) + t0 + mt * 16 + grp * 4 + r4;
            const float* uvq = UVQ + (size_t)row * 512;
#pragma unroll
            for (int a = 0; a < 4; a++) {
                acc[mt][2 * a][r4]     = uvq[h4[a]] + uk_r[a];
                acc[mt][2 * a + 1][r4] = uvq[256 + h4[a]] + vk_r[a];
            }
        }
    }
    float s1 = 0.f, s2 = 0.f;
    // fragment-major staging offset: slot = (srow>>4)*64 + (tid&3)*16 + (srow&15)
    int ao = ((((srow >> 4) << 6) | ((tid & 3) << 4) | (srow & 15)) << 3);
    __syncthreads();   // kk ready
    // ---- stage ALL 8 K-chunks (q * kk -> hi/lo bf16) ----
#pragma unroll
    for (int kc = 0; kc < 8; kc++) {
        float q8[8], kv[8];
        *(float4*)&q8[0] = *(const float4*)&qrow[kc * 32];
        *(float4*)&q8[4] = *(const float4*)&qrow[kc * 32 + 4];
        *(float4*)&kv[0] = *(const float4*)&kk[kc * 32 + scol];
        *(float4*)&kv[4] = *(const float4*)&kk[kc * 32 + scol + 4];
        bf16x8 vh, vl;
        short htmp[2], ltmp[2];
#pragma unroll
        for (int i = 0; i < 4; i++) {
            float a = q8[2 * i] * kv[2 * i];
            float c = q8[2 * i + 1] * kv[2 * i + 1];
            s1 += a + c;
            s2 = fmaf(a, a, s2); s2 = fmaf(c, c, s2);
            split2(a, c, htmp, ltmp);
            vh[2 * i] = htmp[0]; vh[2 * i + 1] = htmp[1];
            vl[2 * i] = ltmp[0]; vl[2 * i + 1] = ltmp[1];
        }
        *(bf16x8*)&Ah[kc][ao] = vh;
        *(bf16x8*)&Al[kc][ao] = vl;
    }
    // LN stats (before the single barrier)
    s1 += __shfl_xor(s1, 1, 64); s1 += __shfl_xor(s1, 2, 64);
    s2 += __shfl_xor(s2, 1, 64); s2 += __shfl_xor(s2, 2, 64);
    if ((tid & 3) == 0) {
        int row = (b << 10) + t0 + srow;
        float sq = s1 + ws[OFF_SQ + row] + ws[OFF_SQ + 2048 + bj];
        float sq2 = s2 + ws[OFF_SQ2 + row] + ws[OFF_SQ2 + 2048 + bj];
        float muv = sq * (1.0f / 768.0f);
        float ex2 = sq2 * (1.0f / 768.0f);
        mu_s[srow] = muv;
        inv_s[srow] = 1.0f / sqrtf(ex2 - muv * muv + 1e-5f);
    }
    __syncthreads();   // the ONLY staging barrier
    // ---- MFMA: 8 K-chunks, kc order rotated per block (L2 de-lockstep) ----
#pragma unroll
    for (int ii = 0; ii < 8; ii++) {
        int kcg = (ii + rot8) & 7;           // runtime — addresses only
        bf16x8 afh[4], afl[4];
#pragma unroll
        for (int mt = 0; mt < 4; mt++) {
            int fo = ((mt << 6) | l) << 3;   // contiguous per-lane fragment
            afh[mt] = *(const bf16x8*)&Ah[kcg][fo];
            afl[mt] = *(const bf16x8*)&Al[kcg][fo];
        }
        const bf16x8* bpc = bpk + ((size_t)(kcg * 32 + ntg0) * 2) * 64 + l;
#pragma unroll
        for (int nt = 0; nt < 8; nt++) {
            bf16x8 bh = bpc[(size_t)nt * 128];
            bf16x8 bl = bpc[(size_t)nt * 128 + 64];
#pragma unroll
            for (int mt = 0; mt < 4; mt++)
                acc[mt][nt] = __builtin_amdgcn_mfma_f32_16x16x32_bf16(afl[mt], bh, acc[mt][nt], 0, 0, 0);
#pragma unroll
            for (int mt = 0; mt < 4; mt++)
                acc[mt][nt] = __builtin_amdgcn_mfma_f32_16x16x32_bf16(afh[mt], bl, acc[mt][nt], 0, 0, 0);
#pragma unroll
            for (int mt = 0; mt < 4; mt++)
                acc[mt][nt] = __builtin_amdgcn_mfma_f32_16x16x32_bf16(afh[mt], bh, acc[mt][nt], 0, 0, 0);
        }
    }
    // ---- epilogue: U = fma(invv, acc - muv*wgu, cu); gelu; wave-reduce ----
#pragma unroll
    for (int mt = 0; mt < 4; mt++) {
#pragma unroll
        for (int r4 = 0; r4 < 4; r4++) {
            int r = mt * 16 + grp * 4 + r4;
            float muv = mu_s[r], invv = inv_s[r];
            float part = 0.f;
#pragma unroll
            for (int a = 0; a < 4; a++) {
                float U = fmaf(invv, fmaf(-muv, wgu_r[a], acc[mt][2 * a][r4]), cu_r[a]);
                float V = fmaf(invv, fmaf(-muv, wgv_r[a], acc[mt][2 * a + 1][r4]), cv_r[a]);
                part = fmaf(wo_r[a] * U, gelu_fast(V), part);
            }
            part += __shfl_xor(part, 1, 64);
            part += __shfl_xor(part, 2, 64);
            part += __shfl_xor(part, 4, 64);
            part += __shfl_xor(part, 8, 64);
            if (c15 == 0) part_s[w][r] = part;
        }
    }
    __syncthreads();
    if (tid < 64) {
        float v = bo[0] + part_s[0][tid] + part_s[1][tid] + part_s[2][tid] + part_s[3][tid];
        logits[(size_t)((b << 10) + t0 + tid) * 64 + j] = v;
    }
}

// ---- k5: topk + softmax + bias expansion; 4 rows/block; pow2 fast path ----
__global__ __launch_bounds__(256) void topk_bias(const float* __restrict__ logits,
                                                 float* __restrict__ bias,
                                                 const int* __restrict__ p_cl,
                                                 const int* __restrict__ p_L) {
    int wv = threadIdx.x >> 6, lane = threadIdx.x & 63;
    int row = blockIdx.x * 4 + wv;
    int t = row & 1023;
    __shared__ float pcb[4][64];
    float L = logits[(size_t)row * 64 + lane];
    float mx = L;
#pragma unroll
    for (int off = 32; off > 0; off >>= 1) mx = fmaxf(mx, __shfl_xor(mx, off, 64));
    float e = expf(L - mx);
    float s = wave_reduce_add(e);
    pcb[wv][lane] = -8.0f * (1.0f - e / s);
    bool valid = (lane >= 5) && ((lane - 5) <= t);
    float val = (lane >= 5) ? (valid ? L : -INFINITY) : -INFINITY;
    int idv = (lane >= 5) ? lane : (1 << 28);
    unsigned long long selmask = 0x1Full;
    for (int it = 0; it < 11; it++) {
        float bv = val; int bi = idv;
#pragma unroll
        for (int off = 32; off > 0; off >>= 1) {
            float ov = __shfl_xor(bv, off, 64);
            int oi = __shfl_xor(bi, off, 64);
            if (ov > bv || (ov == bv && oi < bi)) { bv = ov; bi = oi; }
        }
        selmask |= 1ull << bi;
        if (lane == bi) { val = -INFINITY; idv = (1 << 27); }
    }
    int clen = p_cl[0], Lctx = p_L[0];
    int nch1 = (Lctx + clen - 1) / clen - 1;
    bool p2 = (clen & (clen - 1)) == 0;
    int sh = 31 - __clz(clen);
    float* brow = bias + (size_t)row * Lctx;
    if ((Lctx & 3) == 0) {
        float4* brow4 = (float4*)brow;
        for (int q = lane; q < (Lctx >> 2); q += 64) {
            float o[4];
#pragma unroll
            for (int i = 0; i < 4; i++) {
                int ll = 4 * q + i;
                unsigned cq = p2 ? ((unsigned)ll >> sh) : ((unsigned)ll / (unsigned)clen);
                int c = min(min(cq, (unsigned)nch1), 63u);
                float v;
                if (ll > t) v = -1e30f;   // finite sentinel: ref -inf, diff must stay non-nan
                else if ((selmask >> c) & 1ull) v = 0.0f;
                else v = pcb[wv][c];
                o[i] = v;
            }
            brow4[q] = *(float4*)&o[0];
        }
    } else {
        for (int ll = lane; ll < Lctx; ll += 64) {
            unsigned cq = p2 ? ((unsigned)ll >> sh) : ((unsigned)ll / (unsigned)clen);
            int c = min(min(cq, (unsigned)nch1), 63u);
            float v;
            if (ll > t) v = -1e30f;
            else if ((selmask >> c) & 1ull) v = 0.0f;
            else v = pcb[wv][c];
            brow[ll] = v;
        }
    }
}

extern "C" void kernel_launch(void* const* d_in, const int* in_sizes, int n_in,
                              void* d_out, int out_size, void* d_ws, size_t ws_size,
                              hipStream_t stream) {
    const float* Q   = (const float*)d_in[0];
    const float* Kin = (const float*)d_in[1];
    const float* Wq  = (const float*)d_in[2];
    const float* Wk  = (const float*)d_in[3];
    const float* g   = (const float*)d_in[4];
    const float* lb  = (const float*)d_in[5];
    const float* Wu  = (const float*)d_in[6];
    const float* bu  = (const float*)d_in[7];
    const float* Wv  = (const float*)d_in[8];
    const float* bv  = (const float*)d_in[9];
    const float* Wo  = (const float*)d_in[10];
    const float* bo  = (const float*)d_in[11];
    const int* p_cl  = (const int*)d_in[12];
    const int* p_L   = (const int*)d_in[13];
    float* ws = (float*)d_ws;
    float* logits = (float*)d_out;
    float* bias = (float*)d_out + (size_t)2 * 1024 * 64;   // 131072

    prep<<<2688, 256, 0, stream>>>(Wq, Wk, Wu, Wv, g, lb, bu, bv, ws, bias);
    proj_mfma<<<dim3(4, 68, 2), 256, 0, stream>>>(Q, Kin, bias, ws);
    uv_mfma<<<dim3(8, 68), 256, 0, stream>>>(ws, bias);
    main_mfma<<<2048, 256, 0, stream>>>(ws, bias, Wo, bo, logits);
    topk_bias<<<512, 256, 0, stream>>>(logits, bias, p_cl, p_L);
}

// Round 11
// 221.584 us; speedup vs baseline: 1.1394x; 1.0139x over previous
//
#include <hip/hip_runtime.h>
#include <hip/hip_bf16.h>
#include <math.h>

#define H3 768

// ---- ws layout (floats) ----
#define OFF_Q     0u        // 2048*256  (pre-summed q, atomic-accumulated)
#define OFF_K     524288u   // 128*256
#define OFF_UVK   557056u   // 128*512
#define OFF_SQ    622592u   // 2176 row sums (q rows 0..2047, k rows at 2048+bj)
#define OFF_SQ2   624768u   // 2176
#define OFF_WGU   626944u   // 256
#define OFF_WGV   627200u   // 256
#define OFF_CU    627456u   // 256
#define OFF_CV    627712u   // 256

// ---- scratch inside d_out's bias region (2097152 floats), all consumed
// before topk_bias overwrites it ----
#define BO_UVQ   0u          // 1048576  (2048x512 fp32)
#define BO_WQF   1048576u    // 262144   (Wq frags hi/lo, NTG=16, K=1024)
#define BO_WKF   1310720u    // 262144
#define BO_BPK   1572864u    // 131072   (qk-weight frags, NTG=32, K=256)
#define BO_WQBF  1703936u    // 131072
#define BO_WKBF  1835008u    // 131072   end 1966080 < 2097152

typedef __attribute__((ext_vector_type(8))) short bf16x8;
typedef __attribute__((ext_vector_type(4))) float f32x4;

__device__ __forceinline__ float bf2f(short s) {
    return __uint_as_float(((unsigned)(unsigned short)s) << 16);
}
union bfu { __hip_bfloat162 h; short2 s; };
__device__ __forceinline__ void split2(float a, float b, short* hi2, short* lo2) {
    bfu h; h.h = __float22bfloat162_rn(float2{a, b});
    float fa = bf2f(h.s.x), fb = bf2f(h.s.y);
    bfu l; l.h = __float22bfloat162_rn(float2{a - fa, b - fb});
    hi2[0] = h.s.x; hi2[1] = h.s.y;
    lo2[0] = l.s.x; lo2[1] = l.s.y;
}
__device__ __forceinline__ void split8(const float* v, bf16x8* vh, bf16x8* vl) {
    short h2[2], l2[2];
#pragma unroll
    for (int i = 0; i < 4; i++) {
        split2(v[2 * i], v[2 * i + 1], h2, l2);
        (*vh)[2 * i] = h2[0]; (*vh)[2 * i + 1] = h2[1];
        (*vl)[2 * i] = l2[0]; (*vl)[2 * i + 1] = l2[1];
    }
}

// branchless exact-gelu via A&S 7.1.26 erf (abs err ~1.5e-7)
__device__ __forceinline__ float gelu_fast(float v) {
    float ar = v * 0.70710678118654752440f;
    float a = fabsf(ar);
    float t = __builtin_amdgcn_rcpf(fmaf(0.3275911f, a, 1.0f));
    float p = fmaf(fmaf(fmaf(fmaf(1.061405429f, t, -1.453152027f), t,
                             1.421413741f), t, -0.284496736f), t, 0.254829592f) * t;
    float e = __expf(-ar * ar);
    float er = fmaf(-p, e, 1.0f);
    er = copysignf(er, ar);
    return 0.5f * v * (1.0f + er);
}

__device__ __forceinline__ float wave_reduce_add(float v) {
#pragma unroll
    for (int off = 32; off > 0; off >>= 1) v += __shfl_xor(v, off, 64);
    return v;
}

// ---- k1: prep — R12 verbatim: per-h scalars + weight frag scatters + q/K
// zeroing (zeroing blocks run concurrently with scatter work) ----
__global__ __launch_bounds__(256) void prep(const float* __restrict__ Wq,
                                            const float* __restrict__ Wk,
                                            const float* __restrict__ Wu,
                                            const float* __restrict__ Wv,
                                            const float* __restrict__ g,
                                            const float* __restrict__ lb,
                                            const float* __restrict__ bu,
                                            const float* __restrict__ bv,
                                            float* __restrict__ ws,
                                            float* __restrict__ bsc) {
    int tid = threadIdx.x;
    int bid = blockIdx.x;
    if (bid >= 512) {
        ws[(bid - 512) * 256 + tid] = 0.0f;   // zero q/K region [0, 557056)
        return;
    }
    if (bid < 64) {
        int h = bid * 4 + (tid >> 6);
        int lane = tid & 63;
        float su = 0.f, sv = 0.f, tu = 0.f, tv = 0.f;
#pragma unroll
        for (int i = 0; i < 12; i++) {
            int c = lane + 64 * i;
            float gg = g[c], bb = lb[c];
            float wu = Wu[h * H3 + c], wv = Wv[h * H3 + c];
            su += wu * gg; sv += wv * gg; tu += wu * bb; tv += wv * bb;
        }
        su = wave_reduce_add(su); sv = wave_reduce_add(sv);
        tu = wave_reduce_add(tu); tv = wave_reduce_add(tv);
        if (lane == 0) {
            ws[OFF_WGU + h] = su; ws[OFF_WGV + h] = sv;
            ws[OFF_CU + h] = tu + bu[h]; ws[OFF_CV + h] = tv + bv[h];
        }
        return;
    }
    float v8[8];
    bf16x8 vh, vl;
    if (bid < 320) {
        // WqF (64..191) / WkF (192..319): N=256, K=1024, NTG=16
        const float* W; bf16x8* dst;
        int idx;
        if (bid < 192) { idx = (bid - 64) * 256 + tid; W = Wq; dst = (bf16x8*)(bsc + BO_WQF); }
        else { idx = (bid - 192) * 256 + tid; W = Wk; dst = (bf16x8*)(bsc + BO_WKF); }
        int n = idx >> 7, k8 = idx & 127;
        const float* src = W + (size_t)n * 1024 + k8 * 8;
        *(float4*)&v8[0] = *(const float4*)src;
        *(float4*)&v8[4] = *(const float4*)(src + 4);
        split8(v8, &vh, &vl);
        int kc = k8 >> 2, grp = k8 & 3, lane = grp * 16 + (n & 15), ntg = n >> 4;
        size_t s0 = ((size_t)(kc * 16 + ntg) * 2) * 64 + lane;
        dst[s0] = vh; dst[s0 + 64] = vl;
        return;
    }
    // N=512, K=256, NTG=32 frag matrices from Wu/Wv*g
    int idx, c0;
    bf16x8* dst;
    int n;
    if (bid < 384) {        // WQBf
        idx = (bid - 320) * 256 + tid;
        n = idx >> 5; c0 = (idx & 31) * 8;
        dst = (bf16x8*)(bsc + BO_WQBF);
    } else if (bid < 448) { // WKBf
        idx = (bid - 384) * 256 + tid;
        n = idx >> 5; c0 = 256 + (idx & 31) * 8;
        dst = (bf16x8*)(bsc + BO_WKBF);
    } else {                // BPK (interleaved U/V n-mapping)
        idx = (bid - 448) * 256 + tid;
        n = idx >> 5; c0 = 512 + (idx & 31) * 8;
        dst = (bf16x8*)(bsc + BO_BPK);
    }
    int h, uv;
    if (bid < 448) { uv = (n < 256) ? 0 : 1; h = (n < 256) ? n : n - 256; }
    else {
        int ntg0 = n >> 4, cc = n & 15;
        uv = ntg0 & 1;
        h = ((ntg0 >> 3) << 6) | (((ntg0 >> 1) & 3) << 4) | cc;
    }
    const float* W = uv ? Wv : Wu;
#pragma unroll
    for (int i = 0; i < 8; i++) v8[i] = W[(size_t)h * H3 + c0 + i] * g[c0 + i];
    split8(v8, &vh, &vl);
    int k8 = (c0 & 255) >> 3;
    int kc = k8 >> 2, grp = k8 & 3, lane = grp * 16 + (n & 15), ntg = n >> 4;
    size_t s0 = ((size_t)(kc * 32 + ntg) * 2) * 64 + lane;
    dst[s0] = vh; dst[s0 + 64] = vl;
}

// ---- k2: projection MFMA — R12 verbatim: K-split x2, atomicAdd accumulate
// (exactly 2 commutative fp32 adds per element -> deterministic). 544 blocks
// = balanced 2.1/CU. ----
__global__ __launch_bounds__(256) void proj_mfma(const float* __restrict__ Q,
                                                 const float* __restrict__ Kin,
                                                 const float* __restrict__ bsc,
                                                 float* __restrict__ ws) {
    __shared__ __align__(16) short Ah[2][32 * 40], Al[2][32 * 40];
    int tid = threadIdx.x, bx = blockIdx.x, by = blockIdx.y, ks = blockIdx.z;
    const float* A; float* C; const bf16x8* BF;
    if (by < 64) {
        A = Q + (size_t)by * 32 * 1024;
        C = ws + OFF_Q + (size_t)by * 32 * 256;
        BF = (const bf16x8*)(bsc + BO_WQF);
    } else {
        A = Kin + (size_t)(by - 64) * 32 * 1024;
        C = ws + OFF_K + (size_t)(by - 64) * 32 * 256;
        BF = (const bf16x8*)(bsc + BO_WKF);
    }
    int w = tid >> 6, l = tid & 63, c15 = l & 15, grp = l >> 4;
    int mt = w & 1, np = w >> 1;
    int srow = tid >> 3, scol = (tid & 7) * 4;
    const float* arow = A + (size_t)srow * 1024 + ks * 512 + scol;
    f32x4 acc[2];
    acc[0] = (f32x4){0.f, 0.f, 0.f, 0.f};
    acc[1] = (f32x4){0.f, 0.f, 0.f, 0.f};
    float4 a4 = *(const float4*)&arow[0];
    for (int kc = 0; kc < 16; kc++) {
        int pb = kc & 1;
        short h4[4], l4[4];
        split2(a4.x, a4.y, &h4[0], &l4[0]);
        split2(a4.z, a4.w, &h4[2], &l4[2]);
        int ao = srow * 40 + scol;
        *(short4*)&Ah[pb][ao] = *(short4*)&h4[0];
        *(short4*)&Al[pb][ao] = *(short4*)&l4[0];
        if (kc < 15) a4 = *(const float4*)&arow[(kc + 1) * 32];
        __syncthreads();
        int fo = (mt * 16 + c15) * 40 + grp * 8;
        bf16x8 afh = *(const bf16x8*)&Ah[pb][fo];
        bf16x8 afl = *(const bf16x8*)&Al[pb][fo];
        int kcg = ks * 16 + kc;
        bf16x8 bh[2], bl[2];
#pragma unroll
        for (int i = 0; i < 2; i++) {
            int ntg = bx * 4 + 2 * np + i;
            size_t fi = ((size_t)(kcg * 16 + ntg) * 2) * 64 + l;
            bh[i] = BF[fi]; bl[i] = BF[fi + 64];
        }
#pragma unroll
        for (int i = 0; i < 2; i++)
            acc[i] = __builtin_amdgcn_mfma_f32_16x16x32_bf16(afl, bh[i], acc[i], 0, 0, 0);
#pragma unroll
        for (int i = 0; i < 2; i++)
            acc[i] = __builtin_amdgcn_mfma_f32_16x16x32_bf16(afh, bl[i], acc[i], 0, 0, 0);
#pragma unroll
        for (int i = 0; i < 2; i++)
            acc[i] = __builtin_amdgcn_mfma_f32_16x16x32_bf16(afh, bh[i], acc[i], 0, 0, 0);
    }
#pragma unroll
    for (int r = 0; r < 4; r++) {
        int rloc = mt * 16 + grp * 4 + r;
#pragma unroll
        for (int i = 0; i < 2; i++)
            atomicAdd(&C[(size_t)rloc * 256 + bx * 64 + (2 * np + i) * 16 + c15], acc[i][r]);
    }
}

// ---- k3: UV GEMM — R22: balanced 32-row blocks (grid (8,68)=544, 2.1/CU),
// proj-style double-buffered LDS (one barrier/kc). ----
__global__ __launch_bounds__(256) void uv_mfma(float* __restrict__ ws,
                                               float* __restrict__ bsc) {
    __shared__ __align__(16) short Ah[2][32 * 40], Al[2][32 * 40];
    int tid = threadIdx.x, bx = blockIdx.x, by = blockIdx.y;
    const float* A; float* C; const bf16x8* BF; int sbase;
    if (by < 64) {
        A = ws + OFF_Q + (size_t)by * 32 * 256;
        C = bsc + BO_UVQ + (size_t)by * 32 * 512;
        BF = (const bf16x8*)(bsc + BO_WQBF);
        sbase = by * 32;
    } else {
        A = ws + OFF_K + (size_t)(by - 64) * 32 * 256;
        C = ws + OFF_UVK + (size_t)(by - 64) * 32 * 512;
        BF = (const bf16x8*)(bsc + BO_WKBF);
        sbase = 2048 + (by - 64) * 32;
    }
    int w = tid >> 6, l = tid & 63, c15 = l & 15, grp = l >> 4;
    int mt = w & 1, np = w >> 1;
    int srow = tid >> 3, scol = (tid & 7) * 4;
    const float* arow = A + (size_t)srow * 256 + scol;
    f32x4 acc[2];
    acc[0] = (f32x4){0.f, 0.f, 0.f, 0.f};
    acc[1] = (f32x4){0.f, 0.f, 0.f, 0.f};
    float s1 = 0.f, s2 = 0.f;
    float4 a4 = *(const float4*)&arow[0];
    for (int kc = 0; kc < 8; kc++) {
        int pb = kc & 1;
        if (bx == 0) {
            s1 += (a4.x + a4.y) + (a4.z + a4.w);
            s2 = fmaf(a4.x, a4.x, s2); s2 = fmaf(a4.y, a4.y, s2);
            s2 = fmaf(a4.z, a4.z, s2); s2 = fmaf(a4.w, a4.w, s2);
        }
        short h4v[4], l4v[4];
        split2(a4.x, a4.y, &h4v[0], &l4v[0]);
        split2(a4.z, a4.w, &h4v[2], &l4v[2]);
        int ao = srow * 40 + scol;
        *(short4*)&Ah[pb][ao] = *(short4*)&h4v[0];
        *(short4*)&Al[pb][ao] = *(short4*)&l4v[0];
        if (kc < 7) a4 = *(const float4*)&arow[(kc + 1) * 32];
        __syncthreads();
        int fo = (mt * 16 + c15) * 40 + grp * 8;
        bf16x8 afh = *(const bf16x8*)&Ah[pb][fo];
        bf16x8 afl = *(const bf16x8*)&Al[pb][fo];
        bf16x8 bh[2], bl[2];
#pragma unroll
        for (int i = 0; i < 2; i++) {
            int ntg = bx * 4 + np * 2 + i;
            size_t fi = ((size_t)(kc * 32 + ntg) * 2) * 64 + l;
            bh[i] = BF[fi]; bl[i] = BF[fi + 64];
        }
#pragma unroll
        for (int i = 0; i < 2; i++)
            acc[i] = __builtin_amdgcn_mfma_f32_16x16x32_bf16(afl, bh[i], acc[i], 0, 0, 0);
#pragma unroll
        for (int i = 0; i < 2; i++)
            acc[i] = __builtin_amdgcn_mfma_f32_16x16x32_bf16(afh, bl[i], acc[i], 0, 0, 0);
#pragma unroll
        for (int i = 0; i < 2; i++)
            acc[i] = __builtin_amdgcn_mfma_f32_16x16x32_bf16(afh, bh[i], acc[i], 0, 0, 0);
    }
    if (bx == 0) {
        s1 += __shfl_xor(s1, 1, 64); s1 += __shfl_xor(s1, 2, 64); s1 += __shfl_xor(s1, 4, 64);
        s2 += __shfl_xor(s2, 1, 64); s2 += __shfl_xor(s2, 2, 64); s2 += __shfl_xor(s2, 4, 64);
        if ((tid & 7) == 0) {
            ws[OFF_SQ + sbase + srow] = s1;
            ws[OFF_SQ2 + sbase + srow] = s2;
        }
    }
#pragma unroll
    for (int i = 0; i < 2; i++)
#pragma unroll
        for (int r = 0; r < 4; r++)
            C[(size_t)(mt * 16 + grp * 4 + r) * 512 + bx * 64 + np * 32 + i * 16 + c15] = acc[i][r];
}

// ---- k4: main split-bf16 MFMA — R23: R18 structure + s_setprio(1) around
// the MFMA cluster (T5). Register-capped at 2 blocks/CU (acc 128 AGPR + 128
// VGPR); the 2 independent blocks drift out of phase -> setprio biases issue
// arbitration toward MFMA waves during the drift window. Zero reg/LDS/
// schedule impact; numerics identical to R18/R20/R22. ----
__global__ __launch_bounds__(256, 2) void main_mfma(const float* __restrict__ ws,
                                                    const float* __restrict__ bsc,
                                                    const float* __restrict__ Wo,
                                                    const float* __restrict__ bo,
                                                    float* __restrict__ logits) {
    __shared__ float kk[256];
    __shared__ __align__(16) short Ah[8][64 * 32];   // 32 KB (fragment-major)
    __shared__ __align__(16) short Al[8][64 * 32];   // 32 KB
    __shared__ float mu_s[64], inv_s[64];
    __shared__ float part_s[4][64];
    int tid = threadIdx.x;
    int bidf = blockIdx.x;
    int ti = ((bidf & 7) << 1) | ((bidf >> 3) & 1);
    int j = (bidf >> 4) & 63;
    int b = bidf >> 10;
    int t0 = ti << 6;
    int bj = (b << 6) | j;
    int rot8 = bidf & 7;
    kk[tid] = ws[OFF_K + bj * 256 + tid];
    int w = tid >> 6, l = tid & 63, c15 = l & 15, grp = l >> 4;
    int srow = tid >> 2, scol = (tid & 3) * 8;
    const float* qrow = ws + OFF_Q + (size_t)((b << 10) + t0 + srow) * 256 + scol;
    const bf16x8* bpk = (const bf16x8*)(bsc + BO_BPK);
    const float* UVQ = bsc + BO_UVQ;
    int ntg0 = w * 8;
    // per-channel scalars + h mapping (early: consumed by acc-init + epilogue)
    float wgu_r[4], wgv_r[4], cu_r[4], cv_r[4], wo_r[4], uk_r[4], vk_r[4];
    int h4[4];
#pragma unroll
    for (int a = 0; a < 4; a++) {
        int h = (w << 6) | (a << 4) | c15;
        h4[a] = h;
        wgu_r[a] = ws[OFF_WGU + h]; wgv_r[a] = ws[OFF_WGV + h];
        cu_r[a] = ws[OFF_CU + h]; cv_r[a] = ws[OFF_CV + h];
        wo_r[a] = Wo[h];
        uk_r[a] = ws[OFF_UVK + (size_t)bj * 512 + h];
        vk_r[a] = ws[OFF_UVK + (size_t)bj * 512 + 256 + h];
    }
    // ---- MFMA C-in init: acc = uvq + uvk (affine base; mu-term stays in
    // epilogue since mu isn't known yet). Loads overlap staging latency. ----
    f32x4 acc[4][8];
#pragma unroll
    for (int mt = 0; mt < 4; mt++) {
#pragma unroll
        for (int r4 = 0; r4 < 4; r4++) {
            int row = (b << 10) + t0 + mt * 16 + grp * 4 + r4;
            const float* uvq = UVQ + (size_t)row * 512;
#pragma unroll
            for (int a = 0; a < 4; a++) {
                acc[mt][2 * a][r4]     = uvq[h4[a]] + uk_r[a];
                acc[mt][2 * a + 1][r4] = uvq[256 + h4[a]] + vk_r[a];
            }
        }
    }
    float s1 = 0.f, s2 = 0.f;
    // fragment-major staging offset: slot = (srow>>4)*64 + (tid&3)*16 + (srow&15)
    int ao = ((((srow >> 4) << 6) | ((tid & 3) << 4) | (srow & 15)) << 3);
    __syncthreads();   // kk ready
    // ---- stage ALL 8 K-chunks (q * kk -> hi/lo bf16) ----
#pragma unroll
    for (int kc = 0; kc < 8; kc++) {
        float q8[8], kv[8];
        *(float4*)&q8[0] = *(const float4*)&qrow[kc * 32];
        *(float4*)&q8[4] = *(const float4*)&qrow[kc * 32 + 4];
        *(float4*)&kv[0] = *(const float4*)&kk[kc * 32 + scol];
        *(float4*)&kv[4] = *(const float4*)&kk[kc * 32 + scol + 4];
        bf16x8 vh, vl;
        short htmp[2], ltmp[2];
#pragma unroll
        for (int i = 0; i < 4; i++) {
            float a = q8[2 * i] * kv[2 * i];
            float c = q8[2 * i + 1] * kv[2 * i + 1];
            s1 += a + c;
            s2 = fmaf(a, a, s2); s2 = fmaf(c, c, s2);
            split2(a, c, htmp, ltmp);
            vh[2 * i] = htmp[0]; vh[2 * i + 1] = htmp[1];
            vl[2 * i] = ltmp[0]; vl[2 * i + 1] = ltmp[1];
        }
        *(bf16x8*)&Ah[kc][ao] = vh;
        *(bf16x8*)&Al[kc][ao] = vl;
    }
    // LN stats (before the single barrier)
    s1 += __shfl_xor(s1, 1, 64); s1 += __shfl_xor(s1, 2, 64);
    s2 += __shfl_xor(s2, 1, 64); s2 += __shfl_xor(s2, 2, 64);
    if ((tid & 3) == 0) {
        int row = (b << 10) + t0 + srow;
        float sq = s1 + ws[OFF_SQ + row] + ws[OFF_SQ + 2048 + bj];
        float sq2 = s2 + ws[OFF_SQ2 + row] + ws[OFF_SQ2 + 2048 + bj];
        float muv = sq * (1.0f / 768.0f);
        float ex2 = sq2 * (1.0f / 768.0f);
        mu_s[srow] = muv;
        inv_s[srow] = 1.0f / sqrtf(ex2 - muv * muv + 1e-5f);
    }
    __syncthreads();   // the ONLY staging barrier
    // ---- MFMA: 8 K-chunks, kc order rotated per block (L2 de-lockstep);
    // setprio(1) biases CU issue arbitration toward these waves when the
    // co-resident block is in its VALU phases ----
    __builtin_amdgcn_s_setprio(1);
#pragma unroll
    for (int ii = 0; ii < 8; ii++) {
        int kcg = (ii + rot8) & 7;           // runtime — addresses only
        bf16x8 afh[4], afl[4];
#pragma unroll
        for (int mt = 0; mt < 4; mt++) {
            int fo = ((mt << 6) | l) << 3;   // contiguous per-lane fragment
            afh[mt] = *(const bf16x8*)&Ah[kcg][fo];
            afl[mt] = *(const bf16x8*)&Al[kcg][fo];
        }
        const bf16x8* bpc = bpk + ((size_t)(kcg * 32 + ntg0) * 2) * 64 + l;
#pragma unroll
        for (int nt = 0; nt < 8; nt++) {
            bf16x8 bh = bpc[(size_t)nt * 128];
            bf16x8 bl = bpc[(size_t)nt * 128 + 64];
#pragma unroll
            for (int mt = 0; mt < 4; mt++)
                acc[mt][nt] = __builtin_amdgcn_mfma_f32_16x16x32_bf16(afl[mt], bh, acc[mt][nt], 0, 0, 0);
#pragma unroll
            for (int mt = 0; mt < 4; mt++)
                acc[mt][nt] = __builtin_amdgcn_mfma_f32_16x16x32_bf16(afh[mt], bl, acc[mt][nt], 0, 0, 0);
#pragma unroll
            for (int mt = 0; mt < 4; mt++)
                acc[mt][nt] = __builtin_amdgcn_mfma_f32_16x16x32_bf16(afh[mt], bh, acc[mt][nt], 0, 0, 0);
        }
    }
    __builtin_amdgcn_s_setprio(0);
    // ---- epilogue: U = fma(invv, acc - muv*wgu, cu); gelu; wave-reduce ----
#pragma unroll
    for (int mt = 0; mt < 4; mt++) {
#pragma unroll
        for (int r4 = 0; r4 < 4; r4++) {
            int r = mt * 16 + grp * 4 + r4;
            float muv = mu_s[r], invv = inv_s[r];
            float part = 0.f;
#pragma unroll
            for (int a = 0; a < 4; a++) {
                float U = fmaf(invv, fmaf(-muv, wgu_r[a], acc[mt][2 * a][r4]), cu_r[a]);
                float V = fmaf(invv, fmaf(-muv, wgv_r[a], acc[mt][2 * a + 1][r4]), cv_r[a]);
                part = fmaf(wo_r[a] * U, gelu_fast(V), part);
            }
            part += __shfl_xor(part, 1, 64);
            part += __shfl_xor(part, 2, 64);
            part += __shfl_xor(part, 4, 64);
            part += __shfl_xor(part, 8, 64);
            if (c15 == 0) part_s[w][r] = part;
        }
    }
    __syncthreads();
    if (tid < 64) {
        float v = bo[0] + part_s[0][tid] + part_s[1][tid] + part_s[2][tid] + part_s[3][tid];
        logits[(size_t)((b << 10) + t0 + tid) * 64 + j] = v;
    }
}

// ---- k5: topk + softmax + bias expansion; 4 rows/block; pow2 fast path ----
__global__ __launch_bounds__(256) void topk_bias(const float* __restrict__ logits,
                                                 float* __restrict__ bias,
                                                 const int* __restrict__ p_cl,
                                                 const int* __restrict__ p_L) {
    int wv = threadIdx.x >> 6, lane = threadIdx.x & 63;
    int row = blockIdx.x * 4 + wv;
    int t = row & 1023;
    __shared__ float pcb[4][64];
    float L = logits[(size_t)row * 64 + lane];
    float mx = L;
#pragma unroll
    for (int off = 32; off > 0; off >>= 1) mx = fmaxf(mx, __shfl_xor(mx, off, 64));
    float e = expf(L - mx);
    float s = wave_reduce_add(e);
    pcb[wv][lane] = -8.0f * (1.0f - e / s);
    bool valid = (lane >= 5) && ((lane - 5) <= t);
    float val = (lane >= 5) ? (valid ? L : -INFINITY) : -INFINITY;
    int idv = (lane >= 5) ? lane : (1 << 28);
    unsigned long long selmask = 0x1Full;
    for (int it = 0; it < 11; it++) {
        float bv = val; int bi = idv;
#pragma unroll
        for (int off = 32; off > 0; off >>= 1) {
            float ov = __shfl_xor(bv, off, 64);
            int oi = __shfl_xor(bi, off, 64);
            if (ov > bv || (ov == bv && oi < bi)) { bv = ov; bi = oi; }
        }
        selmask |= 1ull << bi;
        if (lane == bi) { val = -INFINITY; idv = (1 << 27); }
    }
    int clen = p_cl[0], Lctx = p_L[0];
    int nch1 = (Lctx + clen - 1) / clen - 1;
    bool p2 = (clen & (clen - 1)) == 0;
    int sh = 31 - __clz(clen);
    float* brow = bias + (size_t)row * Lctx;
    if ((Lctx & 3) == 0) {
        float4* brow4 = (float4*)brow;
        for (int q = lane; q < (Lctx >> 2); q += 64) {
            float o[4];
#pragma unroll
            for (int i = 0; i < 4; i++) {
                int ll = 4 * q + i;
                unsigned cq = p2 ? ((unsigned)ll >> sh) : ((unsigned)ll / (unsigned)clen);
                int c = min(min(cq, (unsigned)nch1), 63u);
                float v;
                if (ll > t) v = -1e30f;   // finite sentinel: ref -inf, diff must stay non-nan
                else if ((selmask >> c) & 1ull) v = 0.0f;
                else v = pcb[wv][c];
                o[i] = v;
            }
            brow4[q] = *(float4*)&o[0];
        }
    } else {
        for (int ll = lane; ll < Lctx; ll += 64) {
            unsigned cq = p2 ? ((unsigned)ll >> sh) : ((unsigned)ll / (unsigned)clen);
            int c = min(min(cq, (unsigned)nch1), 63u);
            float v;
            if (ll > t) v = -1e30f;
            else if ((selmask >> c) & 1ull) v = 0.0f;
            else v = pcb[wv][c];
            brow[ll] = v;
        }
    }
}

extern "C" void kernel_launch(void* const* d_in, const int* in_sizes, int n_in,
                              void* d_out, int out_size, void* d_ws, size_t ws_size,
                              hipStream_t stream) {
    const float* Q   = (const float*)d_in[0];
    const float* Kin = (const float*)d_in[1];
    const float* Wq  = (const float*)d_in[2];
    const float* Wk  = (const float*)d_in[3];
    const float* g   = (const float*)d_in[4];
    const float* lb  = (const float*)d_in[5];
    const float* Wu  = (const float*)d_in[6];
    const float* bu  = (const float*)d_in[7];
    const float* Wv  = (const float*)d_in[8];
    const float* bv  = (const float*)d_in[9];
    const float* Wo  = (const float*)d_in[10];
    const float* bo  = (const float*)d_in[11];
    const int* p_cl  = (const int*)d_in[12];
    const int* p_L   = (const int*)d_in[13];
    float* ws = (float*)d_ws;
    float* logits = (float*)d_out;
    float* bias = (float*)d_out + (size_t)2 * 1024 * 64;   // 131072

    prep<<<2688, 256, 0, stream>>>(Wq, Wk, Wu, Wv, g, lb, bu, bv, ws, bias);
    proj_mfma<<<dim3(4, 68, 2), 256, 0, stream>>>(Q, Kin, bias, ws);
    uv_mfma<<<dim3(8, 68), 256, 0, stream>>>(ws, bias);
    main_mfma<<<2048, 256, 0, stream>>>(ws, bias, Wo, bo, logits);
    topk_bias<<<512, 256, 0, stream>>>(logits, bias, p_cl, p_L);
}

// Round 12
// 221.376 us; speedup vs baseline: 1.1405x; 1.0009x over previous
//
#include <hip/hip_runtime.h>
#include <hip/hip_bf16.h>
#include <math.h>

#define H3 768

// ---- ws layout (floats) ----
#define OFF_Q     0u        // 2048*256  (pre-summed q, atomic-accumulated)
#define OFF_K     524288u   // 128*256
#define OFF_UVK   557056u   // 128*512
#define OFF_SQ    622592u   // 2176 row sums (q rows 0..2047, k rows at 2048+bj)
#define OFF_SQ2   624768u   // 2176
#define OFF_WGU   626944u   // 256
#define OFF_WGV   627200u   // 256
#define OFF_CU    627456u   // 256
#define OFF_CV    627712u   // 256

// ---- scratch inside d_out's bias region (2097152 floats), all consumed
// before topk_bias overwrites it ----
#define BO_UVQ   0u          // 1048576  (2048x512 fp32)
#define BO_WQF   1048576u    // 262144   (Wq frags hi/lo, NTG=16, K=1024)
#define BO_WKF   1310720u    // 262144
#define BO_BPK   1572864u    // 131072   (qk-weight frags, NTG=32, K=256)
#define BO_WQBF  1703936u    // 131072
#define BO_WKBF  1835008u    // 131072   end 1966080 < 2097152

typedef __attribute__((ext_vector_type(8))) short bf16x8;
typedef __attribute__((ext_vector_type(4))) float f32x4;

__device__ __forceinline__ float bf2f(short s) {
    return __uint_as_float(((unsigned)(unsigned short)s) << 16);
}
union bfu { __hip_bfloat162 h; short2 s; };
__device__ __forceinline__ void split2(float a, float b, short* hi2, short* lo2) {
    bfu h; h.h = __float22bfloat162_rn(float2{a, b});
    float fa = bf2f(h.s.x), fb = bf2f(h.s.y);
    bfu l; l.h = __float22bfloat162_rn(float2{a - fa, b - fb});
    hi2[0] = h.s.x; hi2[1] = h.s.y;
    lo2[0] = l.s.x; lo2[1] = l.s.y;
}
__device__ __forceinline__ void split8(const float* v, bf16x8* vh, bf16x8* vl) {
    short h2[2], l2[2];
#pragma unroll
    for (int i = 0; i < 4; i++) {
        split2(v[2 * i], v[2 * i + 1], h2, l2);
        (*vh)[2 * i] = h2[0]; (*vh)[2 * i + 1] = h2[1];
        (*vl)[2 * i] = l2[0]; (*vl)[2 * i + 1] = l2[1];
    }
}

// branchless exact-gelu via A&S 7.1.26 erf (abs err ~1.5e-7)
__device__ __forceinline__ float gelu_fast(float v) {
    float ar = v * 0.70710678118654752440f;
    float a = fabsf(ar);
    float t = __builtin_amdgcn_rcpf(fmaf(0.3275911f, a, 1.0f));
    float p = fmaf(fmaf(fmaf(fmaf(1.061405429f, t, -1.453152027f), t,
                             1.421413741f), t, -0.284496736f), t, 0.254829592f) * t;
    float e = __expf(-ar * ar);
    float er = fmaf(-p, e, 1.0f);
    er = copysignf(er, ar);
    return 0.5f * v * (1.0f + er);
}

__device__ __forceinline__ float wave_reduce_add(float v) {
#pragma unroll
    for (int off = 32; off > 0; off >>= 1) v += __shfl_xor(v, off, 64);
    return v;
}

// ---- k1: prep — R12 verbatim: per-h scalars + weight frag scatters + q/K
// zeroing (zeroing blocks run concurrently with scatter work) ----
__global__ __launch_bounds__(256) void prep(const float* __restrict__ Wq,
                                            const float* __restrict__ Wk,
                                            const float* __restrict__ Wu,
                                            const float* __restrict__ Wv,
                                            const float* __restrict__ g,
                                            const float* __restrict__ lb,
                                            const float* __restrict__ bu,
                                            const float* __restrict__ bv,
                                            float* __restrict__ ws,
                                            float* __restrict__ bsc) {
    int tid = threadIdx.x;
    int bid = blockIdx.x;
    if (bid >= 512) {
        ws[(bid - 512) * 256 + tid] = 0.0f;   // zero q/K region [0, 557056)
        return;
    }
    if (bid < 64) {
        int h = bid * 4 + (tid >> 6);
        int lane = tid & 63;
        float su = 0.f, sv = 0.f, tu = 0.f, tv = 0.f;
#pragma unroll
        for (int i = 0; i < 12; i++) {
            int c = lane + 64 * i;
            float gg = g[c], bb = lb[c];
            float wu = Wu[h * H3 + c], wv = Wv[h * H3 + c];
            su += wu * gg; sv += wv * gg; tu += wu * bb; tv += wv * bb;
        }
        su = wave_reduce_add(su); sv = wave_reduce_add(sv);
        tu = wave_reduce_add(tu); tv = wave_reduce_add(tv);
        if (lane == 0) {
            ws[OFF_WGU + h] = su; ws[OFF_WGV + h] = sv;
            ws[OFF_CU + h] = tu + bu[h]; ws[OFF_CV + h] = tv + bv[h];
        }
        return;
    }
    float v8[8];
    bf16x8 vh, vl;
    if (bid < 320) {
        // WqF (64..191) / WkF (192..319): N=256, K=1024, NTG=16
        const float* W; bf16x8* dst;
        int idx;
        if (bid < 192) { idx = (bid - 64) * 256 + tid; W = Wq; dst = (bf16x8*)(bsc + BO_WQF); }
        else { idx = (bid - 192) * 256 + tid; W = Wk; dst = (bf16x8*)(bsc + BO_WKF); }
        int n = idx >> 7, k8 = idx & 127;
        const float* src = W + (size_t)n * 1024 + k8 * 8;
        *(float4*)&v8[0] = *(const float4*)src;
        *(float4*)&v8[4] = *(const float4*)(src + 4);
        split8(v8, &vh, &vl);
        int kc = k8 >> 2, grp = k8 & 3, lane = grp * 16 + (n & 15), ntg = n >> 4;
        size_t s0 = ((size_t)(kc * 16 + ntg) * 2) * 64 + lane;
        dst[s0] = vh; dst[s0 + 64] = vl;
        return;
    }
    // N=512, K=256, NTG=32 frag matrices from Wu/Wv*g
    int idx, c0;
    bf16x8* dst;
    int n;
    if (bid < 384) {        // WQBf
        idx = (bid - 320) * 256 + tid;
        n = idx >> 5; c0 = (idx & 31) * 8;
        dst = (bf16x8*)(bsc + BO_WQBF);
    } else if (bid < 448) { // WKBf
        idx = (bid - 384) * 256 + tid;
        n = idx >> 5; c0 = 256 + (idx & 31) * 8;
        dst = (bf16x8*)(bsc + BO_WKBF);
    } else {                // BPK (interleaved U/V n-mapping)
        idx = (bid - 448) * 256 + tid;
        n = idx >> 5; c0 = 512 + (idx & 31) * 8;
        dst = (bf16x8*)(bsc + BO_BPK);
    }
    int h, uv;
    if (bid < 448) { uv = (n < 256) ? 0 : 1; h = (n < 256) ? n : n - 256; }
    else {
        int ntg0 = n >> 4, cc = n & 15;
        uv = ntg0 & 1;
        h = ((ntg0 >> 3) << 6) | (((ntg0 >> 1) & 3) << 4) | cc;
    }
    const float* W = uv ? Wv : Wu;
#pragma unroll
    for (int i = 0; i < 8; i++) v8[i] = W[(size_t)h * H3 + c0 + i] * g[c0 + i];
    split8(v8, &vh, &vl);
    int k8 = (c0 & 255) >> 3;
    int kc = k8 >> 2, grp = k8 & 3, lane = grp * 16 + (n & 15), ntg = n >> 4;
    size_t s0 = ((size_t)(kc * 32 + ntg) * 2) * 64 + lane;
    dst[s0] = vh; dst[s0 + 64] = vl;
}

// ---- k2: projection MFMA — R12 structure + R24 setprio(T5) on the MFMA
// cluster: ~2.1 blocks/CU drift out of phase; MFMA waves win arbitration
// during other blocks' split2/staging VALU. ----
__global__ __launch_bounds__(256) void proj_mfma(const float* __restrict__ Q,
                                                 const float* __restrict__ Kin,
                                                 const float* __restrict__ bsc,
                                                 float* __restrict__ ws) {
    __shared__ __align__(16) short Ah[2][32 * 40], Al[2][32 * 40];
    int tid = threadIdx.x, bx = blockIdx.x, by = blockIdx.y, ks = blockIdx.z;
    const float* A; float* C; const bf16x8* BF;
    if (by < 64) {
        A = Q + (size_t)by * 32 * 1024;
        C = ws + OFF_Q + (size_t)by * 32 * 256;
        BF = (const bf16x8*)(bsc + BO_WQF);
    } else {
        A = Kin + (size_t)(by - 64) * 32 * 1024;
        C = ws + OFF_K + (size_t)(by - 64) * 32 * 256;
        BF = (const bf16x8*)(bsc + BO_WKF);
    }
    int w = tid >> 6, l = tid & 63, c15 = l & 15, grp = l >> 4;
    int mt = w & 1, np = w >> 1;
    int srow = tid >> 3, scol = (tid & 7) * 4;
    const float* arow = A + (size_t)srow * 1024 + ks * 512 + scol;
    f32x4 acc[2];
    acc[0] = (f32x4){0.f, 0.f, 0.f, 0.f};
    acc[1] = (f32x4){0.f, 0.f, 0.f, 0.f};
    float4 a4 = *(const float4*)&arow[0];
    for (int kc = 0; kc < 16; kc++) {
        int pb = kc & 1;
        short h4[4], l4[4];
        split2(a4.x, a4.y, &h4[0], &l4[0]);
        split2(a4.z, a4.w, &h4[2], &l4[2]);
        int ao = srow * 40 + scol;
        *(short4*)&Ah[pb][ao] = *(short4*)&h4[0];
        *(short4*)&Al[pb][ao] = *(short4*)&l4[0];
        if (kc < 15) a4 = *(const float4*)&arow[(kc + 1) * 32];
        __syncthreads();
        int fo = (mt * 16 + c15) * 40 + grp * 8;
        bf16x8 afh = *(const bf16x8*)&Ah[pb][fo];
        bf16x8 afl = *(const bf16x8*)&Al[pb][fo];
        int kcg = ks * 16 + kc;
        bf16x8 bh[2], bl[2];
#pragma unroll
        for (int i = 0; i < 2; i++) {
            int ntg = bx * 4 + 2 * np + i;
            size_t fi = ((size_t)(kcg * 16 + ntg) * 2) * 64 + l;
            bh[i] = BF[fi]; bl[i] = BF[fi + 64];
        }
        __builtin_amdgcn_s_setprio(1);
#pragma unroll
        for (int i = 0; i < 2; i++)
            acc[i] = __builtin_amdgcn_mfma_f32_16x16x32_bf16(afl, bh[i], acc[i], 0, 0, 0);
#pragma unroll
        for (int i = 0; i < 2; i++)
            acc[i] = __builtin_amdgcn_mfma_f32_16x16x32_bf16(afh, bl[i], acc[i], 0, 0, 0);
#pragma unroll
        for (int i = 0; i < 2; i++)
            acc[i] = __builtin_amdgcn_mfma_f32_16x16x32_bf16(afh, bh[i], acc[i], 0, 0, 0);
        __builtin_amdgcn_s_setprio(0);
    }
#pragma unroll
    for (int r = 0; r < 4; r++) {
        int rloc = mt * 16 + grp * 4 + r;
#pragma unroll
        for (int i = 0; i < 2; i++)
            atomicAdd(&C[(size_t)rloc * 256 + bx * 64 + (2 * np + i) * 16 + c15], acc[i][r]);
    }
}

// ---- k3: UV GEMM — R22 structure (balanced 544 blocks, double-buffered LDS,
// one barrier/kc) + R24 setprio(T5) on the MFMA cluster. ----
__global__ __launch_bounds__(256) void uv_mfma(float* __restrict__ ws,
                                               float* __restrict__ bsc) {
    __shared__ __align__(16) short Ah[2][32 * 40], Al[2][32 * 40];
    int tid = threadIdx.x, bx = blockIdx.x, by = blockIdx.y;
    const float* A; float* C; const bf16x8* BF; int sbase;
    if (by < 64) {
        A = ws + OFF_Q + (size_t)by * 32 * 256;
        C = bsc + BO_UVQ + (size_t)by * 32 * 512;
        BF = (const bf16x8*)(bsc + BO_WQBF);
        sbase = by * 32;
    } else {
        A = ws + OFF_K + (size_t)(by - 64) * 32 * 256;
        C = ws + OFF_UVK + (size_t)(by - 64) * 32 * 512;
        BF = (const bf16x8*)(bsc + BO_WKBF);
        sbase = 2048 + (by - 64) * 32;
    }
    int w = tid >> 6, l = tid & 63, c15 = l & 15, grp = l >> 4;
    int mt = w & 1, np = w >> 1;
    int srow = tid >> 3, scol = (tid & 7) * 4;
    const float* arow = A + (size_t)srow * 256 + scol;
    f32x4 acc[2];
    acc[0] = (f32x4){0.f, 0.f, 0.f, 0.f};
    acc[1] = (f32x4){0.f, 0.f, 0.f, 0.f};
    float s1 = 0.f, s2 = 0.f;
    float4 a4 = *(const float4*)&arow[0];
    for (int kc = 0; kc < 8; kc++) {
        int pb = kc & 1;
        if (bx == 0) {
            s1 += (a4.x + a4.y) + (a4.z + a4.w);
            s2 = fmaf(a4.x, a4.x, s2); s2 = fmaf(a4.y, a4.y, s2);
            s2 = fmaf(a4.z, a4.z, s2); s2 = fmaf(a4.w, a4.w, s2);
        }
        short h4v[4], l4v[4];
        split2(a4.x, a4.y, &h4v[0], &l4v[0]);
        split2(a4.z, a4.w, &h4v[2], &l4v[2]);
        int ao = srow * 40 + scol;
        *(short4*)&Ah[pb][ao] = *(short4*)&h4v[0];
        *(short4*)&Al[pb][ao] = *(short4*)&l4v[0];
        if (kc < 7) a4 = *(const float4*)&arow[(kc + 1) * 32];
        __syncthreads();
        int fo = (mt * 16 + c15) * 40 + grp * 8;
        bf16x8 afh = *(const bf16x8*)&Ah[pb][fo];
        bf16x8 afl = *(const bf16x8*)&Al[pb][fo];
        bf16x8 bh[2], bl[2];
#pragma unroll
        for (int i = 0; i < 2; i++) {
            int ntg = bx * 4 + np * 2 + i;
            size_t fi = ((size_t)(kc * 32 + ntg) * 2) * 64 + l;
            bh[i] = BF[fi]; bl[i] = BF[fi + 64];
        }
        __builtin_amdgcn_s_setprio(1);
#pragma unroll
        for (int i = 0; i < 2; i++)
            acc[i] = __builtin_amdgcn_mfma_f32_16x16x32_bf16(afl, bh[i], acc[i], 0, 0, 0);
#pragma unroll
        for (int i = 0; i < 2; i++)
            acc[i] = __builtin_amdgcn_mfma_f32_16x16x32_bf16(afh, bl[i], acc[i], 0, 0, 0);
#pragma unroll
        for (int i = 0; i < 2; i++)
            acc[i] = __builtin_amdgcn_mfma_f32_16x16x32_bf16(afh, bh[i], acc[i], 0, 0, 0);
        __builtin_amdgcn_s_setprio(0);
    }
    if (bx == 0) {
        s1 += __shfl_xor(s1, 1, 64); s1 += __shfl_xor(s1, 2, 64); s1 += __shfl_xor(s1, 4, 64);
        s2 += __shfl_xor(s2, 1, 64); s2 += __shfl_xor(s2, 2, 64); s2 += __shfl_xor(s2, 4, 64);
        if ((tid & 7) == 0) {
            ws[OFF_SQ + sbase + srow] = s1;
            ws[OFF_SQ2 + sbase + srow] = s2;
        }
    }
#pragma unroll
    for (int i = 0; i < 2; i++)
#pragma unroll
        for (int r = 0; r < 4; r++)
            C[(size_t)(mt * 16 + grp * 4 + r) * 512 + bx * 64 + np * 32 + i * 16 + c15] = acc[i][r];
}

// ---- k4: main split-bf16 MFMA — R23 verbatim (best: 118.2us). R18 structure
// + setprio(1) around the MFMA cluster (T5): 2 independent blocks/CU drift
// out of phase; setprio biases issue toward MFMA waves during the drift. ----
__global__ __launch_bounds__(256, 2) void main_mfma(const float* __restrict__ ws,
                                                    const float* __restrict__ bsc,
                                                    const float* __restrict__ Wo,
                                                    const float* __restrict__ bo,
                                                    float* __restrict__ logits) {
    __shared__ float kk[256];
    __shared__ __align__(16) short Ah[8][64 * 32];   // 32 KB (fragment-major)
    __shared__ __align__(16) short Al[8][64 * 32];   // 32 KB
    __shared__ float mu_s[64], inv_s[64];
    __shared__ float part_s[4][64];
    int tid = threadIdx.x;
    int bidf = blockIdx.x;
    int ti = ((bidf & 7) << 1) | ((bidf >> 3) & 1);
    int j = (bidf >> 4) & 63;
    int b = bidf >> 10;
    int t0 = ti << 6;
    int bj = (b << 6) | j;
    int rot8 = bidf & 7;
    kk[tid] = ws[OFF_K + bj * 256 + tid];
    int w = tid >> 6, l = tid & 63, c15 = l & 15, grp = l >> 4;
    int srow = tid >> 2, scol = (tid & 3) * 8;
    const float* qrow = ws + OFF_Q + (size_t)((b << 10) + t0 + srow) * 256 + scol;
    const bf16x8* bpk = (const bf16x8*)(bsc + BO_BPK);
    const float* UVQ = bsc + BO_UVQ;
    int ntg0 = w * 8;
    // per-channel scalars + h mapping (early: consumed by acc-init + epilogue)
    float wgu_r[4], wgv_r[4], cu_r[4], cv_r[4], wo_r[4], uk_r[4], vk_r[4];
    int h4[4];
#pragma unroll
    for (int a = 0; a < 4; a++) {
        int h = (w << 6) | (a << 4) | c15;
        h4[a] = h;
        wgu_r[a] = ws[OFF_WGU + h]; wgv_r[a] = ws[OFF_WGV + h];
        cu_r[a] = ws[OFF_CU + h]; cv_r[a] = ws[OFF_CV + h];
        wo_r[a] = Wo[h];
        uk_r[a] = ws[OFF_UVK + (size_t)bj * 512 + h];
        vk_r[a] = ws[OFF_UVK + (size_t)bj * 512 + 256 + h];
    }
    // ---- MFMA C-in init: acc = uvq + uvk (affine base; mu-term stays in
    // epilogue since mu isn't known yet). Loads overlap staging latency. ----
    f32x4 acc[4][8];
#pragma unroll
    for (int mt = 0; mt < 4; mt++) {
#pragma unroll
        for (int r4 = 0; r4 < 4; r4++) {
            int row = (b << 10) + t0 + mt * 16 + grp * 4 + r4;
            const float* uvq = UVQ + (size_t)row * 512;
#pragma unroll
            for (int a = 0; a < 4; a++) {
                acc[mt][2 * a][r4]     = uvq[h4[a]] + uk_r[a];
                acc[mt][2 * a + 1][r4] = uvq[256 + h4[a]] + vk_r[a];
            }
        }
    }
    float s1 = 0.f, s2 = 0.f;
    // fragment-major staging offset: slot = (srow>>4)*64 + (tid&3)*16 + (srow&15)
    int ao = ((((srow >> 4) << 6) | ((tid & 3) << 4) | (srow & 15)) << 3);
    __syncthreads();   // kk ready
    // ---- stage ALL 8 K-chunks (q * kk -> hi/lo bf16) ----
#pragma unroll
    for (int kc = 0; kc < 8; kc++) {
        float q8[8], kv[8];
        *(float4*)&q8[0] = *(const float4*)&qrow[kc * 32];
        *(float4*)&q8[4] = *(const float4*)&qrow[kc * 32 + 4];
        *(float4*)&kv[0] = *(const float4*)&kk[kc * 32 + scol];
        *(float4*)&kv[4] = *(const float4*)&kk[kc * 32 + scol + 4];
        bf16x8 vh, vl;
        short htmp[2], ltmp[2];
#pragma unroll
        for (int i = 0; i < 4; i++) {
            float a = q8[2 * i] * kv[2 * i];
            float c = q8[2 * i + 1] * kv[2 * i + 1];
            s1 += a + c;
            s2 = fmaf(a, a, s2); s2 = fmaf(c, c, s2);
            split2(a, c, htmp, ltmp);
            vh[2 * i] = htmp[0]; vh[2 * i + 1] = htmp[1];
            vl[2 * i] = ltmp[0]; vl[2 * i + 1] = ltmp[1];
        }
        *(bf16x8*)&Ah[kc][ao] = vh;
        *(bf16x8*)&Al[kc][ao] = vl;
    }
    // LN stats (before the single barrier)
    s1 += __shfl_xor(s1, 1, 64); s1 += __shfl_xor(s1, 2, 64);
    s2 += __shfl_xor(s2, 1, 64); s2 += __shfl_xor(s2, 2, 64);
    if ((tid & 3) == 0) {
        int row = (b << 10) + t0 + srow;
        float sq = s1 + ws[OFF_SQ + row] + ws[OFF_SQ + 2048 + bj];
        float sq2 = s2 + ws[OFF_SQ2 + row] + ws[OFF_SQ2 + 2048 + bj];
        float muv = sq * (1.0f / 768.0f);
        float ex2 = sq2 * (1.0f / 768.0f);
        mu_s[srow] = muv;
        inv_s[srow] = 1.0f / sqrtf(ex2 - muv * muv + 1e-5f);
    }
    __syncthreads();   // the ONLY staging barrier
    // ---- MFMA: 8 K-chunks, kc order rotated per block (L2 de-lockstep);
    // setprio(1) biases CU issue arbitration toward these waves when the
    // co-resident block is in its VALU phases ----
    __builtin_amdgcn_s_setprio(1);
#pragma unroll
    for (int ii = 0; ii < 8; ii++) {
        int kcg = (ii + rot8) & 7;           // runtime — addresses only
        bf16x8 afh[4], afl[4];
#pragma unroll
        for (int mt = 0; mt < 4; mt++) {
            int fo = ((mt << 6) | l) << 3;   // contiguous per-lane fragment
            afh[mt] = *(const bf16x8*)&Ah[kcg][fo];
            afl[mt] = *(const bf16x8*)&Al[kcg][fo];
        }
        const bf16x8* bpc = bpk + ((size_t)(kcg * 32 + ntg0) * 2) * 64 + l;
#pragma unroll
        for (int nt = 0; nt < 8; nt++) {
            bf16x8 bh = bpc[(size_t)nt * 128];
            bf16x8 bl = bpc[(size_t)nt * 128 + 64];
#pragma unroll
            for (int mt = 0; mt < 4; mt++)
                acc[mt][nt] = __builtin_amdgcn_mfma_f32_16x16x32_bf16(afl[mt], bh, acc[mt][nt], 0, 0, 0);
#pragma unroll
            for (int mt = 0; mt < 4; mt++)
                acc[mt][nt] = __builtin_amdgcn_mfma_f32_16x16x32_bf16(afh[mt], bl, acc[mt][nt], 0, 0, 0);
#pragma unroll
            for (int mt = 0; mt < 4; mt++)
                acc[mt][nt] = __builtin_amdgcn_mfma_f32_16x16x32_bf16(afh[mt], bh, acc[mt][nt], 0, 0, 0);
        }
    }
    __builtin_amdgcn_s_setprio(0);
    // ---- epilogue: U = fma(invv, acc - muv*wgu, cu); gelu; wave-reduce ----
#pragma unroll
    for (int mt = 0; mt < 4; mt++) {
#pragma unroll
        for (int r4 = 0; r4 < 4; r4++) {
            int r = mt * 16 + grp * 4 + r4;
            float muv = mu_s[r], invv = inv_s[r];
            float part = 0.f;
#pragma unroll
            for (int a = 0; a < 4; a++) {
                float U = fmaf(invv, fmaf(-muv, wgu_r[a], acc[mt][2 * a][r4]), cu_r[a]);
                float V = fmaf(invv, fmaf(-muv, wgv_r[a], acc[mt][2 * a + 1][r4]), cv_r[a]);
                part = fmaf(wo_r[a] * U, gelu_fast(V), part);
            }
            part += __shfl_xor(part, 1, 64);
            part += __shfl_xor(part, 2, 64);
            part += __shfl_xor(part, 4, 64);
            part += __shfl_xor(part, 8, 64);
            if (c15 == 0) part_s[w][r] = part;
        }
    }
    __syncthreads();
    if (tid < 64) {
        float v = bo[0] + part_s[0][tid] + part_s[1][tid] + part_s[2][tid] + part_s[3][tid];
        logits[(size_t)((b << 10) + t0 + tid) * 64 + j] = v;
    }
}

// ---- k5: topk + softmax + bias expansion; 4 rows/block; pow2 fast path ----
__global__ __launch_bounds__(256) void topk_bias(const float* __restrict__ logits,
                                                 float* __restrict__ bias,
                                                 const int* __restrict__ p_cl,
                                                 const int* __restrict__ p_L) {
    int wv = threadIdx.x >> 6, lane = threadIdx.x & 63;
    int row = blockIdx.x * 4 + wv;
    int t = row & 1023;
    __shared__ float pcb[4][64];
    float L = logits[(size_t)row * 64 + lane];
    float mx = L;
#pragma unroll
    for (int off = 32; off > 0; off >>= 1) mx = fmaxf(mx, __shfl_xor(mx, off, 64));
    float e = expf(L - mx);
    float s = wave_reduce_add(e);
    pcb[wv][lane] = -8.0f * (1.0f - e / s);
    bool valid = (lane >= 5) && ((lane - 5) <= t);
    float val = (lane >= 5) ? (valid ? L : -INFINITY) : -INFINITY;
    int idv = (lane >= 5) ? lane : (1 << 28);
    unsigned long long selmask = 0x1Full;
    for (int it = 0; it < 11; it++) {
        float bv = val; int bi = idv;
#pragma unroll
        for (int off = 32; off > 0; off >>= 1) {
            float ov = __shfl_xor(bv, off, 64);
            int oi = __shfl_xor(bi, off, 64);
            if (ov > bv || (ov == bv && oi < bi)) { bv = ov; bi = oi; }
        }
        selmask |= 1ull << bi;
        if (lane == bi) { val = -INFINITY; idv = (1 << 27); }
    }
    int clen = p_cl[0], Lctx = p_L[0];
    int nch1 = (Lctx + clen - 1) / clen - 1;
    bool p2 = (clen & (clen - 1)) == 0;
    int sh = 31 - __clz(clen);
    float* brow = bias + (size_t)row * Lctx;
    if ((Lctx & 3) == 0) {
        float4* brow4 = (float4*)brow;
        for (int q = lane; q < (Lctx >> 2); q += 64) {
            float o[4];
#pragma unroll
            for (int i = 0; i < 4; i++) {
                int ll = 4 * q + i;
                unsigned cq = p2 ? ((unsigned)ll >> sh) : ((unsigned)ll / (unsigned)clen);
                int c = min(min(cq, (unsigned)nch1), 63u);
                float v;
                if (ll > t) v = -1e30f;   // finite sentinel: ref -inf, diff must stay non-nan
                else if ((selmask >> c) & 1ull) v = 0.0f;
                else v = pcb[wv][c];
                o[i] = v;
            }
            brow4[q] = *(float4*)&o[0];
        }
    } else {
        for (int ll = lane; ll < Lctx; ll += 64) {
            unsigned cq = p2 ? ((unsigned)ll >> sh) : ((unsigned)ll / (unsigned)clen);
            int c = min(min(cq, (unsigned)nch1), 63u);
            float v;
            if (ll > t) v = -1e30f;
            else if ((selmask >> c) & 1ull) v = 0.0f;
            else v = pcb[wv][c];
            brow[ll] = v;
        }
    }
}

extern "C" void kernel_launch(void* const* d_in, const int* in_sizes, int n_in,
                              void* d_out, int out_size, void* d_ws, size_t ws_size,
                              hipStream_t stream) {
    const float* Q   = (const float*)d_in[0];
    const float* Kin = (const float*)d_in[1];
    const float* Wq  = (const float*)d_in[2];
    const float* Wk  = (const float*)d_in[3];
    const float* g   = (const float*)d_in[4];
    const float* lb  = (const float*)d_in[5];
    const float* Wu  = (const float*)d_in[6];
    const float* bu  = (const float*)d_in[7];
    const float* Wv  = (const float*)d_in[8];
    const float* bv  = (const float*)d_in[9];
    const float* Wo  = (const float*)d_in[10];
    const float* bo  = (const float*)d_in[11];
    const int* p_cl  = (const int*)d_in[12];
    const int* p_L   = (const int*)d_in[13];
    float* ws = (float*)d_ws;
    float* logits = (float*)d_out;
    float* bias = (float*)d_out + (size_t)2 * 1024 * 64;   // 131072

    prep<<<2688, 256, 0, stream>>>(Wq, Wk, Wu, Wv, g, lb, bu, bv, ws, bias);
    proj_mfma<<<dim3(4, 68, 2), 256, 0, stream>>>(Q, Kin, bias, ws);
    uv_mfma<<<dim3(8, 68), 256, 0, stream>>>(ws, bias);
    main_mfma<<<2048, 256, 0, stream>>>(ws, bias, Wo, bo, logits);
    topk_bias<<<512, 256, 0, stream>>>(logits, bias, p_cl, p_L);
}

// Round 13
// 219.929 us; speedup vs baseline: 1.1480x; 1.0066x over previous
//
#include <hip/hip_runtime.h>
#include <hip/hip_bf16.h>
#include <math.h>

#define H3 768

// ---- ws layout (floats) ----
#define OFF_Q     0u        // 2048*256  (pre-summed q, atomic-accumulated)
#define OFF_K     524288u   // 128*256
#define OFF_UVK   557056u   // 128*512
#define OFF_SQ    622592u   // 2176 row sums (q rows 0..2047, k rows at 2048+bj)
#define OFF_SQ2   624768u   // 2176
#define OFF_WGU   626944u   // 256
#define OFF_WGV   627200u   // 256
#define OFF_CU    627456u   // 256
#define OFF_CV    627712u   // 256

// ---- scratch inside d_out's bias region (2097152 floats), all consumed
// before topk_bias overwrites it ----
#define BO_UVQ   0u          // 1048576  (2048x512 fp32)
#define BO_WQF   1048576u    // 262144   (Wq frags hi/lo, NTG=16, K=1024)
#define BO_WKF   1310720u    // 262144
#define BO_BPK   1572864u    // 131072   (qk-weight frags, NTG=32, K=256)
#define BO_WQBF  1703936u    // 131072
#define BO_WKBF  1835008u    // 131072   end 1966080 < 2097152

typedef __attribute__((ext_vector_type(8))) short bf16x8;
typedef __attribute__((ext_vector_type(4))) float f32x4;

__device__ __forceinline__ float bf2f(short s) {
    return __uint_as_float(((unsigned)(unsigned short)s) << 16);
}
union bfu { __hip_bfloat162 h; short2 s; };
__device__ __forceinline__ void split2(float a, float b, short* hi2, short* lo2) {
    bfu h; h.h = __float22bfloat162_rn(float2{a, b});
    float fa = bf2f(h.s.x), fb = bf2f(h.s.y);
    bfu l; l.h = __float22bfloat162_rn(float2{a - fa, b - fb});
    hi2[0] = h.s.x; hi2[1] = h.s.y;
    lo2[0] = l.s.x; lo2[1] = l.s.y;
}
__device__ __forceinline__ void split8(const float* v, bf16x8* vh, bf16x8* vl) {
    short h2[2], l2[2];
#pragma unroll
    for (int i = 0; i < 4; i++) {
        split2(v[2 * i], v[2 * i + 1], h2, l2);
        (*vh)[2 * i] = h2[0]; (*vh)[2 * i + 1] = h2[1];
        (*vl)[2 * i] = l2[0]; (*vl)[2 * i + 1] = l2[1];
    }
}

// branchless exact-gelu via A&S 7.1.26 erf (abs err ~1.5e-7)
__device__ __forceinline__ float gelu_fast(float v) {
    float ar = v * 0.70710678118654752440f;
    float a = fabsf(ar);
    float t = __builtin_amdgcn_rcpf(fmaf(0.3275911f, a, 1.0f));
    float p = fmaf(fmaf(fmaf(fmaf(1.061405429f, t, -1.453152027f), t,
                             1.421413741f), t, -0.284496736f), t, 0.254829592f) * t;
    float e = __expf(-ar * ar);
    float er = fmaf(-p, e, 1.0f);
    er = copysignf(er, ar);
    return 0.5f * v * (1.0f + er);
}

__device__ __forceinline__ float wave_reduce_add(float v) {
#pragma unroll
    for (int off = 32; off > 0; off >>= 1) v += __shfl_xor(v, off, 64);
    return v;
}

// ---- k1: prep — R12 verbatim: per-h scalars + weight frag scatters + q/K
// zeroing (zeroing blocks run concurrently with scatter work) ----
__global__ __launch_bounds__(256) void prep(const float* __restrict__ Wq,
                                            const float* __restrict__ Wk,
                                            const float* __restrict__ Wu,
                                            const float* __restrict__ Wv,
                                            const float* __restrict__ g,
                                            const float* __restrict__ lb,
                                            const float* __restrict__ bu,
                                            const float* __restrict__ bv,
                                            float* __restrict__ ws,
                                            float* __restrict__ bsc) {
    int tid = threadIdx.x;
    int bid = blockIdx.x;
    if (bid >= 512) {
        ws[(bid - 512) * 256 + tid] = 0.0f;   // zero q/K region [0, 557056)
        return;
    }
    if (bid < 64) {
        int h = bid * 4 + (tid >> 6);
        int lane = tid & 63;
        float su = 0.f, sv = 0.f, tu = 0.f, tv = 0.f;
#pragma unroll
        for (int i = 0; i < 12; i++) {
            int c = lane + 64 * i;
            float gg = g[c], bb = lb[c];
            float wu = Wu[h * H3 + c], wv = Wv[h * H3 + c];
            su += wu * gg; sv += wv * gg; tu += wu * bb; tv += wv * bb;
        }
        su = wave_reduce_add(su); sv = wave_reduce_add(sv);
        tu = wave_reduce_add(tu); tv = wave_reduce_add(tv);
        if (lane == 0) {
            ws[OFF_WGU + h] = su; ws[OFF_WGV + h] = sv;
            ws[OFF_CU + h] = tu + bu[h]; ws[OFF_CV + h] = tv + bv[h];
        }
        return;
    }
    float v8[8];
    bf16x8 vh, vl;
    if (bid < 320) {
        // WqF (64..191) / WkF (192..319): N=256, K=1024, NTG=16
        const float* W; bf16x8* dst;
        int idx;
        if (bid < 192) { idx = (bid - 64) * 256 + tid; W = Wq; dst = (bf16x8*)(bsc + BO_WQF); }
        else { idx = (bid - 192) * 256 + tid; W = Wk; dst = (bf16x8*)(bsc + BO_WKF); }
        int n = idx >> 7, k8 = idx & 127;
        const float* src = W + (size_t)n * 1024 + k8 * 8;
        *(float4*)&v8[0] = *(const float4*)src;
        *(float4*)&v8[4] = *(const float4*)(src + 4);
        split8(v8, &vh, &vl);
        int kc = k8 >> 2, grp = k8 & 3, lane = grp * 16 + (n & 15), ntg = n >> 4;
        size_t s0 = ((size_t)(kc * 16 + ntg) * 2) * 64 + lane;
        dst[s0] = vh; dst[s0 + 64] = vl;
        return;
    }
    // N=512, K=256, NTG=32 frag matrices from Wu/Wv*g
    int idx, c0;
    bf16x8* dst;
    int n;
    if (bid < 384) {        // WQBf
        idx = (bid - 320) * 256 + tid;
        n = idx >> 5; c0 = (idx & 31) * 8;
        dst = (bf16x8*)(bsc + BO_WQBF);
    } else if (bid < 448) { // WKBf
        idx = (bid - 384) * 256 + tid;
        n = idx >> 5; c0 = 256 + (idx & 31) * 8;
        dst = (bf16x8*)(bsc + BO_WKBF);
    } else {                // BPK (interleaved U/V n-mapping)
        idx = (bid - 448) * 256 + tid;
        n = idx >> 5; c0 = 512 + (idx & 31) * 8;
        dst = (bf16x8*)(bsc + BO_BPK);
    }
    int h, uv;
    if (bid < 448) { uv = (n < 256) ? 0 : 1; h = (n < 256) ? n : n - 256; }
    else {
        int ntg0 = n >> 4, cc = n & 15;
        uv = ntg0 & 1;
        h = ((ntg0 >> 3) << 6) | (((ntg0 >> 1) & 3) << 4) | cc;
    }
    const float* W = uv ? Wv : Wu;
#pragma unroll
    for (int i = 0; i < 8; i++) v8[i] = W[(size_t)h * H3 + c0 + i] * g[c0 + i];
    split8(v8, &vh, &vl);
    int k8 = (c0 & 255) >> 3;
    int kc = k8 >> 2, grp = k8 & 3, lane = grp * 16 + (n & 15), ntg = n >> 4;
    size_t s0 = ((size_t)(kc * 32 + ntg) * 2) * 64 + lane;
    dst[s0] = vh; dst[s0 + 64] = vl;
}

// ---- k2: projection MFMA — R25: 16-row tiles, grid (2,136,2)=544 balanced.
// Halves A-staging redundancy (bx 4x->2x) and Q L2/HBM reads; same MFMA count
// per wave (16 kc x 2 chains x 3), same atomicAdd accumulation (exactly 2
// commutative adds/element -> deterministic). LDS 5KB -> ~8 blocks/CU. ----
__global__ __launch_bounds__(256) void proj_mfma(const float* __restrict__ Q,
                                                 const float* __restrict__ Kin,
                                                 const float* __restrict__ bsc,
                                                 float* __restrict__ ws) {
    __shared__ __align__(16) short Ah[2][16 * 40], Al[2][16 * 40];
    int tid = threadIdx.x, bx = blockIdx.x, by = blockIdx.y, ks = blockIdx.z;
    const float* A; float* C; const bf16x8* BF;
    if (by < 128) {
        A = Q + (size_t)by * 16 * 1024;
        C = ws + OFF_Q + (size_t)by * 16 * 256;
        BF = (const bf16x8*)(bsc + BO_WQF);
    } else {
        A = Kin + (size_t)(by - 128) * 16 * 1024;
        C = ws + OFF_K + (size_t)(by - 128) * 16 * 256;
        BF = (const bf16x8*)(bsc + BO_WKF);
    }
    int w = tid >> 6, l = tid & 63, c15 = l & 15, grp = l >> 4;
    int srow = tid >> 4, scol = (tid & 15) * 2;
    const float* arow = A + (size_t)srow * 1024 + ks * 512 + scol;
    f32x4 acc[2];
    acc[0] = (f32x4){0.f, 0.f, 0.f, 0.f};
    acc[1] = (f32x4){0.f, 0.f, 0.f, 0.f};
    float2 a2 = *(const float2*)&arow[0];
    for (int kc = 0; kc < 16; kc++) {
        int pb = kc & 1;
        short h2[2], l2[2];
        split2(a2.x, a2.y, h2, l2);
        int ao = srow * 40 + scol;
        *(short2*)&Ah[pb][ao] = *(short2*)&h2[0];
        *(short2*)&Al[pb][ao] = *(short2*)&l2[0];
        if (kc < 15) a2 = *(const float2*)&arow[(kc + 1) * 32];
        __syncthreads();
        int fo = c15 * 40 + grp * 8;
        bf16x8 afh = *(const bf16x8*)&Ah[pb][fo];
        bf16x8 afl = *(const bf16x8*)&Al[pb][fo];
        int kcg = ks * 16 + kc;
        bf16x8 bh[2], bl[2];
#pragma unroll
        for (int i = 0; i < 2; i++) {
            int ntg = bx * 8 + w * 2 + i;
            size_t fi = ((size_t)(kcg * 16 + ntg) * 2) * 64 + l;
            bh[i] = BF[fi]; bl[i] = BF[fi + 64];
        }
        __builtin_amdgcn_s_setprio(1);
#pragma unroll
        for (int i = 0; i < 2; i++)
            acc[i] = __builtin_amdgcn_mfma_f32_16x16x32_bf16(afl, bh[i], acc[i], 0, 0, 0);
#pragma unroll
        for (int i = 0; i < 2; i++)
            acc[i] = __builtin_amdgcn_mfma_f32_16x16x32_bf16(afh, bl[i], acc[i], 0, 0, 0);
#pragma unroll
        for (int i = 0; i < 2; i++)
            acc[i] = __builtin_amdgcn_mfma_f32_16x16x32_bf16(afh, bh[i], acc[i], 0, 0, 0);
        __builtin_amdgcn_s_setprio(0);
    }
#pragma unroll
    for (int r = 0; r < 4; r++) {
        int rloc = grp * 4 + r;
#pragma unroll
        for (int i = 0; i < 2; i++)
            atomicAdd(&C[(size_t)rloc * 256 + (bx * 8 + w * 2 + i) * 16 + c15], acc[i][r]);
    }
}

// ---- k3: UV GEMM — R22 structure (balanced 544 blocks, double-buffered LDS,
// one barrier/kc) + setprio on the MFMA cluster. ----
__global__ __launch_bounds__(256) void uv_mfma(float* __restrict__ ws,
                                               float* __restrict__ bsc) {
    __shared__ __align__(16) short Ah[2][32 * 40], Al[2][32 * 40];
    int tid = threadIdx.x, bx = blockIdx.x, by = blockIdx.y;
    const float* A; float* C; const bf16x8* BF; int sbase;
    if (by < 64) {
        A = ws + OFF_Q + (size_t)by * 32 * 256;
        C = bsc + BO_UVQ + (size_t)by * 32 * 512;
        BF = (const bf16x8*)(bsc + BO_WQBF);
        sbase = by * 32;
    } else {
        A = ws + OFF_K + (size_t)(by - 64) * 32 * 256;
        C = ws + OFF_UVK + (size_t)(by - 64) * 32 * 512;
        BF = (const bf16x8*)(bsc + BO_WKBF);
        sbase = 2048 + (by - 64) * 32;
    }
    int w = tid >> 6, l = tid & 63, c15 = l & 15, grp = l >> 4;
    int mt = w & 1, np = w >> 1;
    int srow = tid >> 3, scol = (tid & 7) * 4;
    const float* arow = A + (size_t)srow * 256 + scol;
    f32x4 acc[2];
    acc[0] = (f32x4){0.f, 0.f, 0.f, 0.f};
    acc[1] = (f32x4){0.f, 0.f, 0.f, 0.f};
    float s1 = 0.f, s2 = 0.f;
    float4 a4 = *(const float4*)&arow[0];
    for (int kc = 0; kc < 8; kc++) {
        int pb = kc & 1;
        if (bx == 0) {
            s1 += (a4.x + a4.y) + (a4.z + a4.w);
            s2 = fmaf(a4.x, a4.x, s2); s2 = fmaf(a4.y, a4.y, s2);
            s2 = fmaf(a4.z, a4.z, s2); s2 = fmaf(a4.w, a4.w, s2);
        }
        short h4v[4], l4v[4];
        split2(a4.x, a4.y, &h4v[0], &l4v[0]);
        split2(a4.z, a4.w, &h4v[2], &l4v[2]);
        int ao = srow * 40 + scol;
        *(short4*)&Ah[pb][ao] = *(short4*)&h4v[0];
        *(short4*)&Al[pb][ao] = *(short4*)&l4v[0];
        if (kc < 7) a4 = *(const float4*)&arow[(kc + 1) * 32];
        __syncthreads();
        int fo = (mt * 16 + c15) * 40 + grp * 8;
        bf16x8 afh = *(const bf16x8*)&Ah[pb][fo];
        bf16x8 afl = *(const bf16x8*)&Al[pb][fo];
        bf16x8 bh[2], bl[2];
#pragma unroll
        for (int i = 0; i < 2; i++) {
            int ntg = bx * 4 + np * 2 + i;
            size_t fi = ((size_t)(kc * 32 + ntg) * 2) * 64 + l;
            bh[i] = BF[fi]; bl[i] = BF[fi + 64];
        }
        __builtin_amdgcn_s_setprio(1);
#pragma unroll
        for (int i = 0; i < 2; i++)
            acc[i] = __builtin_amdgcn_mfma_f32_16x16x32_bf16(afl, bh[i], acc[i], 0, 0, 0);
#pragma unroll
        for (int i = 0; i < 2; i++)
            acc[i] = __builtin_amdgcn_mfma_f32_16x16x32_bf16(afh, bl[i], acc[i], 0, 0, 0);
#pragma unroll
        for (int i = 0; i < 2; i++)
            acc[i] = __builtin_amdgcn_mfma_f32_16x16x32_bf16(afh, bh[i], acc[i], 0, 0, 0);
        __builtin_amdgcn_s_setprio(0);
    }
    if (bx == 0) {
        s1 += __shfl_xor(s1, 1, 64); s1 += __shfl_xor(s1, 2, 64); s1 += __shfl_xor(s1, 4, 64);
        s2 += __shfl_xor(s2, 1, 64); s2 += __shfl_xor(s2, 2, 64); s2 += __shfl_xor(s2, 4, 64);
        if ((tid & 7) == 0) {
            ws[OFF_SQ + sbase + srow] = s1;
            ws[OFF_SQ2 + sbase + srow] = s2;
        }
    }
#pragma unroll
    for (int i = 0; i < 2; i++)
#pragma unroll
        for (int r = 0; r < 4; r++)
            C[(size_t)(mt * 16 + grp * 4 + r) * 512 + bx * 64 + np * 32 + i * 16 + c15] = acc[i][r];
}

// ---- k4: main split-bf16 MFMA — R23 verbatim (best: 118.2us). R18 structure
// + setprio(1) around the MFMA cluster (T5): 2 independent blocks/CU drift
// out of phase; setprio biases issue toward MFMA waves during the drift. ----
__global__ __launch_bounds__(256, 2) void main_mfma(const float* __restrict__ ws,
                                                    const float* __restrict__ bsc,
                                                    const float* __restrict__ Wo,
                                                    const float* __restrict__ bo,
                                                    float* __restrict__ logits) {
    __shared__ float kk[256];
    __shared__ __align__(16) short Ah[8][64 * 32];   // 32 KB (fragment-major)
    __shared__ __align__(16) short Al[8][64 * 32];   // 32 KB
    __shared__ float mu_s[64], inv_s[64];
    __shared__ float part_s[4][64];
    int tid = threadIdx.x;
    int bidf = blockIdx.x;
    int ti = ((bidf & 7) << 1) | ((bidf >> 3) & 1);
    int j = (bidf >> 4) & 63;
    int b = bidf >> 10;
    int t0 = ti << 6;
    int bj = (b << 6) | j;
    int rot8 = bidf & 7;
    kk[tid] = ws[OFF_K + bj * 256 + tid];
    int w = tid >> 6, l = tid & 63, c15 = l & 15, grp = l >> 4;
    int srow = tid >> 2, scol = (tid & 3) * 8;
    const float* qrow = ws + OFF_Q + (size_t)((b << 10) + t0 + srow) * 256 + scol;
    const bf16x8* bpk = (const bf16x8*)(bsc + BO_BPK);
    const float* UVQ = bsc + BO_UVQ;
    int ntg0 = w * 8;
    // per-channel scalars + h mapping (early: consumed by acc-init + epilogue)
    float wgu_r[4], wgv_r[4], cu_r[4], cv_r[4], wo_r[4], uk_r[4], vk_r[4];
    int h4[4];
#pragma unroll
    for (int a = 0; a < 4; a++) {
        int h = (w << 6) | (a << 4) | c15;
        h4[a] = h;
        wgu_r[a] = ws[OFF_WGU + h]; wgv_r[a] = ws[OFF_WGV + h];
        cu_r[a] = ws[OFF_CU + h]; cv_r[a] = ws[OFF_CV + h];
        wo_r[a] = Wo[h];
        uk_r[a] = ws[OFF_UVK + (size_t)bj * 512 + h];
        vk_r[a] = ws[OFF_UVK + (size_t)bj * 512 + 256 + h];
    }
    // ---- MFMA C-in init: acc = uvq + uvk (affine base; mu-term stays in
    // epilogue since mu isn't known yet). Loads overlap staging latency. ----
    f32x4 acc[4][8];
#pragma unroll
    for (int mt = 0; mt < 4; mt++) {
#pragma unroll
        for (int r4 = 0; r4 < 4; r4++) {
            int row = (b << 10) + t0 + mt * 16 + grp * 4 + r4;
            const float* uvq = UVQ + (size_t)row * 512;
#pragma unroll
            for (int a = 0; a < 4; a++) {
                acc[mt][2 * a][r4]     = uvq[h4[a]] + uk_r[a];
                acc[mt][2 * a + 1][r4] = uvq[256 + h4[a]] + vk_r[a];
            }
        }
    }
    float s1 = 0.f, s2 = 0.f;
    // fragment-major staging offset: slot = (srow>>4)*64 + (tid&3)*16 + (srow&15)
    int ao = ((((srow >> 4) << 6) | ((tid & 3) << 4) | (srow & 15)) << 3);
    __syncthreads();   // kk ready
    // ---- stage ALL 8 K-chunks (q * kk -> hi/lo bf16) ----
#pragma unroll
    for (int kc = 0; kc < 8; kc++) {
        float q8[8], kv[8];
        *(float4*)&q8[0] = *(const float4*)&qrow[kc * 32];
        *(float4*)&q8[4] = *(const float4*)&qrow[kc * 32 + 4];
        *(float4*)&kv[0] = *(const float4*)&kk[kc * 32 + scol];
        *(float4*)&kv[4] = *(const float4*)&kk[kc * 32 + scol + 4];
        bf16x8 vh, vl;
        short htmp[2], ltmp[2];
#pragma unroll
        for (int i = 0; i < 4; i++) {
            float a = q8[2 * i] * kv[2 * i];
            float c = q8[2 * i + 1] * kv[2 * i + 1];
            s1 += a + c;
            s2 = fmaf(a, a, s2); s2 = fmaf(c, c, s2);
            split2(a, c, htmp, ltmp);
            vh[2 * i] = htmp[0]; vh[2 * i + 1] = htmp[1];
            vl[2 * i] = ltmp[0]; vl[2 * i + 1] = ltmp[1];
        }
        *(bf16x8*)&Ah[kc][ao] = vh;
        *(bf16x8*)&Al[kc][ao] = vl;
    }
    // LN stats (before the single barrier)
    s1 += __shfl_xor(s1, 1, 64); s1 += __shfl_xor(s1, 2, 64);
    s2 += __shfl_xor(s2, 1, 64); s2 += __shfl_xor(s2, 2, 64);
    if ((tid & 3) == 0) {
        int row = (b << 10) + t0 + srow;
        float sq = s1 + ws[OFF_SQ + row] + ws[OFF_SQ + 2048 + bj];
        float sq2 = s2 + ws[OFF_SQ2 + row] + ws[OFF_SQ2 + 2048 + bj];
        float muv = sq * (1.0f / 768.0f);
        float ex2 = sq2 * (1.0f / 768.0f);
        mu_s[srow] = muv;
        inv_s[srow] = 1.0f / sqrtf(ex2 - muv * muv + 1e-5f);
    }
    __syncthreads();   // the ONLY staging barrier
    // ---- MFMA: 8 K-chunks, kc order rotated per block (L2 de-lockstep);
    // setprio(1) biases CU issue arbitration toward these waves when the
    // co-resident block is in its VALU phases ----
    __builtin_amdgcn_s_setprio(1);
#pragma unroll
    for (int ii = 0; ii < 8; ii++) {
        int kcg = (ii + rot8) & 7;           // runtime — addresses only
        bf16x8 afh[4], afl[4];
#pragma unroll
        for (int mt = 0; mt < 4; mt++) {
            int fo = ((mt << 6) | l) << 3;   // contiguous per-lane fragment
            afh[mt] = *(const bf16x8*)&Ah[kcg][fo];
            afl[mt] = *(const bf16x8*)&Al[kcg][fo];
        }
        const bf16x8* bpc = bpk + ((size_t)(kcg * 32 + ntg0) * 2) * 64 + l;
#pragma unroll
        for (int nt = 0; nt < 8; nt++) {
            bf16x8 bh = bpc[(size_t)nt * 128];
            bf16x8 bl = bpc[(size_t)nt * 128 + 64];
#pragma unroll
            for (int mt = 0; mt < 4; mt++)
                acc[mt][nt] = __builtin_amdgcn_mfma_f32_16x16x32_bf16(afl[mt], bh, acc[mt][nt], 0, 0, 0);
#pragma unroll
            for (int mt = 0; mt < 4; mt++)
                acc[mt][nt] = __builtin_amdgcn_mfma_f32_16x16x32_bf16(afh[mt], bl, acc[mt][nt], 0, 0, 0);
#pragma unroll
            for (int mt = 0; mt < 4; mt++)
                acc[mt][nt] = __builtin_amdgcn_mfma_f32_16x16x32_bf16(afh[mt], bh, acc[mt][nt], 0, 0, 0);
        }
    }
    __builtin_amdgcn_s_setprio(0);
    // ---- epilogue: U = fma(invv, acc - muv*wgu, cu); gelu; wave-reduce ----
#pragma unroll
    for (int mt = 0; mt < 4; mt++) {
#pragma unroll
        for (int r4 = 0; r4 < 4; r4++) {
            int r = mt * 16 + grp * 4 + r4;
            float muv = mu_s[r], invv = inv_s[r];
            float part = 0.f;
#pragma unroll
            for (int a = 0; a < 4; a++) {
                float U = fmaf(invv, fmaf(-muv, wgu_r[a], acc[mt][2 * a][r4]), cu_r[a]);
                float V = fmaf(invv, fmaf(-muv, wgv_r[a], acc[mt][2 * a + 1][r4]), cv_r[a]);
                part = fmaf(wo_r[a] * U, gelu_fast(V), part);
            }
            part += __shfl_xor(part, 1, 64);
            part += __shfl_xor(part, 2, 64);
            part += __shfl_xor(part, 4, 64);
            part += __shfl_xor(part, 8, 64);
            if (c15 == 0) part_s[w][r] = part;
        }
    }
    __syncthreads();
    if (tid < 64) {
        float v = bo[0] + part_s[0][tid] + part_s[1][tid] + part_s[2][tid] + part_s[3][tid];
        logits[(size_t)((b << 10) + t0 + tid) * 64 + j] = v;
    }
}

// ---- k5: topk + softmax + bias expansion; 4 rows/block; pow2 fast path ----
__global__ __launch_bounds__(256) void topk_bias(const float* __restrict__ logits,
                                                 float* __restrict__ bias,
                                                 const int* __restrict__ p_cl,
                                                 const int* __restrict__ p_L) {
    int wv = threadIdx.x >> 6, lane = threadIdx.x & 63;
    int row = blockIdx.x * 4 + wv;
    int t = row & 1023;
    __shared__ float pcb[4][64];
    float L = logits[(size_t)row * 64 + lane];
    float mx = L;
#pragma unroll
    for (int off = 32; off > 0; off >>= 1) mx = fmaxf(mx, __shfl_xor(mx, off, 64));
    float e = expf(L - mx);
    float s = wave_reduce_add(e);
    pcb[wv][lane] = -8.0f * (1.0f - e / s);
    bool valid = (lane >= 5) && ((lane - 5) <= t);
    float val = (lane >= 5) ? (valid ? L : -INFINITY) : -INFINITY;
    int idv = (lane >= 5) ? lane : (1 << 28);
    unsigned long long selmask = 0x1Full;
    for (int it = 0; it < 11; it++) {
        float bv = val; int bi = idv;
#pragma unroll
        for (int off = 32; off > 0; off >>= 1) {
            float ov = __shfl_xor(bv, off, 64);
            int oi = __shfl_xor(bi, off, 64);
            if (ov > bv || (ov == bv && oi < bi)) { bv = ov; bi = oi; }
        }
        selmask |= 1ull << bi;
        if (lane == bi) { val = -INFINITY; idv = (1 << 27); }
    }
    int clen = p_cl[0], Lctx = p_L[0];
    int nch1 = (Lctx + clen - 1) / clen - 1;
    bool p2 = (clen & (clen - 1)) == 0;
    int sh = 31 - __clz(clen);
    float* brow = bias + (size_t)row * Lctx;
    if ((Lctx & 3) == 0) {
        float4* brow4 = (float4*)brow;
        for (int q = lane; q < (Lctx >> 2); q += 64) {
            float o[4];
#pragma unroll
            for (int i = 0; i < 4; i++) {
                int ll = 4 * q + i;
                unsigned cq = p2 ? ((unsigned)ll >> sh) : ((unsigned)ll / (unsigned)clen);
                int c = min(min(cq, (unsigned)nch1), 63u);
                float v;
                if (ll > t) v = -1e30f;   // finite sentinel: ref -inf, diff must stay non-nan
                else if ((selmask >> c) & 1ull) v = 0.0f;
                else v = pcb[wv][c];
                o[i] = v;
            }
            brow4[q] = *(float4*)&o[0];
        }
    } else {
        for (int ll = lane; ll < Lctx; ll += 64) {
            unsigned cq = p2 ? ((unsigned)ll >> sh) : ((unsigned)ll / (unsigned)clen);
            int c = min(min(cq, (unsigned)nch1), 63u);
            float v;
            if (ll > t) v = -1e30f;
            else if ((selmask >> c) & 1ull) v = 0.0f;
            else v = pcb[wv][c];
            brow[ll] = v;
        }
    }
}

extern "C" void kernel_launch(void* const* d_in, const int* in_sizes, int n_in,
                              void* d_out, int out_size, void* d_ws, size_t ws_size,
                              hipStream_t stream) {
    const float* Q   = (const float*)d_in[0];
    const float* Kin = (const float*)d_in[1];
    const float* Wq  = (const float*)d_in[2];
    const float* Wk  = (const float*)d_in[3];
    const float* g   = (const float*)d_in[4];
    const float* lb  = (const float*)d_in[5];
    const float* Wu  = (const float*)d_in[6];
    const float* bu  = (const float*)d_in[7];
    const float* Wv  = (const float*)d_in[8];
    const float* bv  = (const float*)d_in[9];
    const float* Wo  = (const float*)d_in[10];
    const float* bo  = (const float*)d_in[11];
    const int* p_cl  = (const int*)d_in[12];
    const int* p_L   = (const int*)d_in[13];
    float* ws = (float*)d_ws;
    float* logits = (float*)d_out;
    float* bias = (float*)d_out + (size_t)2 * 1024 * 64;   // 131072

    prep<<<2688, 256, 0, stream>>>(Wq, Wk, Wu, Wv, g, lb, bu, bv, ws, bias);
    proj_mfma<<<dim3(2, 136, 2), 256, 0, stream>>>(Q, Kin, bias, ws);
    uv_mfma<<<dim3(8, 68), 256, 0, stream>>>(ws, bias);
    main_mfma<<<2048, 256, 0, stream>>>(ws, bias, Wo, bo, logits);
    topk_bias<<<512, 256, 0, stream>>>(logits, bias, p_cl, p_L);
}